// Round 13
// baseline (807.183 us; speedup 1.0000x reference)
//
#include <hip/hip_runtime.h>

typedef __attribute__((ext_vector_type(8))) short bf16x8;
typedef __attribute__((ext_vector_type(4))) short bf16x4;
typedef __attribute__((ext_vector_type(4))) float f32x4;

#define TFULL 8192
#define RC 128
#define NB 40
#define BATCH 4
#define SKIP_SZ 4096

#define LDS3(p) ((__attribute__((address_space(3))) void*)(p))
#define GLB1(p) ((const __attribute__((address_space(1))) void*)(p))

// ---- single-block kernel LDS ----
#define XPLANE 16384
#define LDS_BYTES (3 * XPLANE)   // 48 KB -> 2 WG/CU (grid-limited)

// ---- fused-pair kernel LDS regions (bytes) ----
#define STGH 48
#define RX 0                     // 112 cols x 256 B : X hi; later gated_{i+1}
#define RG 28672                 // 96 cols : gated_i; later y_lo
#define RY (28672 + 24576)       // 96 cols : y_i hi
#define LDSB (RY + 24576)        // 77824 B -> 2 WG/CU

__device__ __forceinline__ unsigned short f2bf(float f) {
    unsigned u = __builtin_bit_cast(unsigned, f);
    u += 0x7FFFu + ((u >> 16) & 1u);          // round-to-nearest-even
    return (unsigned short)(u >> 16);
}
__device__ __forceinline__ float bf2f(unsigned short h) {
    unsigned u = ((unsigned)h) << 16;
    return __builtin_bit_cast(float, u);
}
// tanh(y)*sigmoid(y) via one fast exp (clamped; saturation exact).
__device__ __forceinline__ float gatef(float y) {
    float yc = fminf(fmaxf(y, -30.f), 30.f);
    float e  = __expf(-yc);
    float e2 = e * e;
    return (1.f - e2) * __builtin_amdgcn_rcpf(1.f + e2)
                      * __builtin_amdgcn_rcpf(1.f + e);
}

// ---------------------------------------------------------------------------
// Pre-pass 1: transpose x [B][128ch][8192col] fp32 -> hi/lo bf16 [B][col][ch]
// ---------------------------------------------------------------------------
__global__ __launch_bounds__(256) void xpose_split(
    const float* __restrict__ x,
    unsigned short* __restrict__ Xh, unsigned short* __restrict__ Xl)
{
    __shared__ float t[32][65];
    const int col0 = blockIdx.x * 64;
    const int ch0  = blockIdx.y * 32;
    const int b    = blockIdx.z;
    const int tid  = threadIdx.x;
    const int tx = tid & 63, ty = tid >> 6;
#pragma unroll
    for (int i = 0; i < 8; ++i) {
        int ch = ty + i * 4;
        t[ch][tx] = x[((size_t)(b * RC + ch0 + ch)) * TFULL + col0 + tx];
    }
    __syncthreads();
    for (int idx = tid; idx < 64 * 32; idx += 256) {
        int col = idx >> 5, ch = idx & 31;
        float v = t[ch][col];
        unsigned short h = f2bf(v);
        unsigned short l = f2bf(v - bf2f(h));
        size_t off = ((size_t)(b * TFULL + col0 + col)) * RC + ch0 + ch;
        Xh[off] = h;
        Xl[off] = l;
    }
}

// ---------------------------------------------------------------------------
// Pre-pass 2: pack weights into per-MFMA-A-fragment layout, hi/lo bf16.
// A[m][k]: lane l holds rows m=16*mf+(l&15), k = 32*ks + (l>>4)*8 + j.
// Dilated k = tap*128 + i. Dst flat: ((blk*KS*8 + ks*8 + mf)*64 + lane)*8 + j.
// ---------------------------------------------------------------------------
__global__ __launch_bounds__(256) void wpack(
    const float* __restrict__ Wd, const float* __restrict__ Wr, const float* __restrict__ Ws,
    unsigned short* __restrict__ Wdh, unsigned short* __restrict__ Wdl,
    unsigned short* __restrict__ Wrh, unsigned short* __restrict__ Wrl,
    unsigned short* __restrict__ Wsh, unsigned short* __restrict__ Wsl)
{
    const int Nd = NB * 4096;
    const int Nr = NB * 2048;
    int id = blockIdx.x * 256 + threadIdx.x;
    const float* src;
    unsigned short *dh, *dl;
    int blk, rloc;
    bool dil = false;
    size_t dbase;
    if (id < Nd)               { dil = true; blk = id >> 12; rloc = id & 4095; dh = Wdh; dl = Wdl; src = Wd; dbase = (size_t)id * 8; }
    else if (id < Nd + Nr)     { int t = id - Nd;      blk = t >> 11; rloc = t & 2047; dh = Wrh; dl = Wrl; src = Wr; dbase = (size_t)t * 8; }
    else if (id < Nd + 2 * Nr) { int t = id - Nd - Nr; blk = t >> 11; rloc = t & 2047; dh = Wsh; dl = Wsl; src = Ws; dbase = (size_t)t * 8; }
    else return;
    const int ks = rloc >> 9, mf = (rloc >> 6) & 7, lane = rloc & 63;
    const int m = mf * 16 + (lane & 15);
    const int kb = ks * 32 + ((lane >> 4) << 3);
    bf16x8 hv, lv;
#pragma unroll
    for (int j = 0; j < 8; ++j) {
        int k = kb + j;
        float w;
        if (dil) {
            int tap = k >> 7, i = k & 127;
            w = src[((((size_t)blk * 128 + m) * 128) + i) * 2 + tap];
        } else {
            w = src[(((size_t)blk * 128 + m) * 128) + k];
        }
        unsigned short h = f2bf(w);
        hv[j] = (short)h;
        lv[j] = (short)f2bf(w - bf2f(h));
    }
    *(bf16x8*)(dh + dbase) = hv;
    *(bf16x8*)(dl + dbase) = lv;
}

// ---------------------------------------------------------------------------
// Single-block step: 1024 thr = 16 waves (2 WG/CU -> 32 waves/CU, chip max).
// wave = (mf = w>>1: 16 out-ch) x (colhalf = w&1: 32 cols). Colhalf twins
// read identical weight fragments simultaneously -> L1 dedups (no extra L2).
// 2-product weights x bf16 X, gated bf16, stream exact hi/lo. Numerics
// bit-identical to the 512-thr version.
// ---------------------------------------------------------------------------
__global__ __launch_bounds__(1024, 8) void wn_step(
    const unsigned short* __restrict__ curh, const unsigned short* __restrict__ curl,
    unsigned short* __restrict__ nxth, unsigned short* __restrict__ nxtl,
    const unsigned short* __restrict__ Wdh_i, const unsigned short* __restrict__ Wdl_i,
    const unsigned short* __restrict__ Wrh_i, const unsigned short* __restrict__ Wrl_i,
    const unsigned short* __restrict__ Wsh_i, const unsigned short* __restrict__ Wsl_i,
    const float* __restrict__ br, const float* __restrict__ bs,
    float* __restrict__ skip, int d, int col0)
{
    __shared__ char lds[LDS_BYTES];

    const int tid   = threadIdx.x;
    const int lane  = tid & 63;
    const int wave  = tid >> 6;          // 0..15
    const int mf    = wave >> 1;         // 0..7
    const int chalf = wave & 1;          // col half
    const int l15   = lane & 15, lq = lane >> 4;
    const int u     = blockIdx.x;
    const int b     = u & 3;
    const int tile0 = col0 + (u >> 2) * 64;
    const size_t xbase = (size_t)b * TFULL * RC;

    // ---- stage BOTH taps (Xh only): 32 x (64-lane x 16B) global_load_lds
#pragma unroll
    for (int r = 0; r < 2; ++r) {
        const int j   = wave * 2 + r;    // 0..31
        const int tap = j >> 4;
        const int c4  = (j & 15) * 4;
        const int col = c4 + lq;
        const int chs = l15 ^ (col & 7);
        int cg_ = tile0 + col;
        cg_ = cg_ > TFULL - 1 ? TFULL - 1 : cg_;
        if (!tap) cg_ -= d;
        const unsigned short* gsrc = curh + xbase + (size_t)cg_ * RC + chs * 8;
        char* ldst = lds + tap * XPLANE + c4 * 256;
        __builtin_amdgcn_global_load_lds(GLB1(gsrc), LDS3(ldst), 16, 0, 0);
    }
    __syncthreads();

    // ---- dilated conv: 8 ks steps, 2-product; this wave's 2 col-frags
    f32x4 acc[2];
#pragma unroll
    for (int nf = 0; nf < 2; ++nf) acc[nf] = (f32x4){0.f, 0.f, 0.f, 0.f};

#pragma unroll
    for (int ks = 0; ks < 8; ++ks) {
        const int tap = ks >> 2;
        const int kk  = ks & 3;
        const size_t wi = ((size_t)(ks * 8 + mf) * 64 + lane) * 8;
        bf16x8 ah = *(const bf16x8*)(Wdh_i + wi);
        bf16x8 al = *(const bf16x8*)(Wdl_i + wi);
#pragma unroll
        for (int nf = 0; nf < 2; ++nf) {
            const int col = (chalf * 2 + nf) * 16 + l15;
            const int byo = (kk * 64 + lq * 16) ^ ((col & 7) << 4);
            bf16x8 bh = *(const bf16x8*)(lds + tap * XPLANE + col * 256 + byo);
            acc[nf] = __builtin_amdgcn_mfma_f32_16x16x32_bf16(ah, bh, acc[nf], 0, 0, 0);
            acc[nf] = __builtin_amdgcn_mfma_f32_16x16x32_bf16(al, bh, acc[nf], 0, 0, 0);
        }
    }

    // ---- gate + write gated (plain bf16) to plane 2
    const int ch0 = mf * 16 + lq * 4;
#pragma unroll
    for (int nf = 0; nf < 2; ++nf) {
        const int n   = (chalf * 2 + nf) * 16 + l15;
        const int byo = (ch0 * 2) ^ ((n & 7) << 4);
        bf16x4 hv;
#pragma unroll
        for (int r = 0; r < 4; ++r)
            hv[r] = (short)f2bf(gatef(acc[nf][r]));
        *(bf16x4*)(lds + 2 * XPLANE + n * 256 + byo) = hv;
    }
    __syncthreads();

    // ---- res & skip 1x1 GEMMs: K = 128 over gated, 2-product each
    f32x4 accr[2], accs[2];
#pragma unroll
    for (int nf = 0; nf < 2; ++nf) {
        accr[nf] = (f32x4){0.f, 0.f, 0.f, 0.f};
        accs[nf] = (f32x4){0.f, 0.f, 0.f, 0.f};
    }
#pragma unroll
    for (int ks = 0; ks < 4; ++ks) {
        const size_t wi = ((size_t)(ks * 8 + mf) * 64 + lane) * 8;
        bf16x8 rh = *(const bf16x8*)(Wrh_i + wi);
        bf16x8 rl = *(const bf16x8*)(Wrl_i + wi);
        bf16x8 sh = *(const bf16x8*)(Wsh_i + wi);
        bf16x8 sl = *(const bf16x8*)(Wsl_i + wi);
#pragma unroll
        for (int nf = 0; nf < 2; ++nf) {
            const int col = (chalf * 2 + nf) * 16 + l15;
            const int byo = (ks * 64 + lq * 16) ^ ((col & 7) << 4);
            bf16x8 g = *(const bf16x8*)(lds + 2 * XPLANE + col * 256 + byo);
            accr[nf] = __builtin_amdgcn_mfma_f32_16x16x32_bf16(rh, g, accr[nf], 0, 0, 0);
            accr[nf] = __builtin_amdgcn_mfma_f32_16x16x32_bf16(rl, g, accr[nf], 0, 0, 0);
            accs[nf] = __builtin_amdgcn_mfma_f32_16x16x32_bf16(sh, g, accs[nf], 0, 0, 0);
            accs[nf] = __builtin_amdgcn_mfma_f32_16x16x32_bf16(sl, g, accs[nf], 0, 0, 0);
        }
    }

    // ---- epilogue: residual add; Xh from plane 1 (tap1), Xl from global.
    const int nt = TFULL - tile0 < 64 ? TFULL - tile0 : 64;
    const float4 brv = *(const float4*)(br + ch0);
    const float4 bsv = *(const float4*)(bs + ch0);
#pragma unroll
    for (int nf = 0; nf < 2; ++nf) {
        const int n = (chalf * 2 + nf) * 16 + l15;
        if (n < nt) {
            const int c = tile0 + n;
            const int byo = (ch0 * 2) ^ ((n & 7) << 4);
            bf16x4 ih = *(const bf16x4*)(lds + XPLANE + n * 256 + byo);
            const size_t off = xbase + (size_t)c * RC + ch0;
            bf16x4 il = *(const bf16x4*)(curl + off);
            bf16x4 oh, ol;
            float sk[4];
#pragma unroll
            for (int r = 0; r < 4; ++r) {
                float inv = bf2f((unsigned short)ih[r]) + bf2f((unsigned short)il[r]);
                float rv = accr[nf][r] + ((const float*)&brv)[r] + inv;
                unsigned short h = f2bf(rv);
                oh[r] = (short)h;
                ol[r] = (short)f2bf(rv - bf2f(h));
                sk[r] = accs[nf][r] + ((const float*)&bsv)[r];
            }
            *(bf16x4*)(nxth + off) = oh;
            *(bf16x4*)(nxtl + off) = ol;
            if (c >= TFULL - SKIP_SZ) {
                float* sp = skip + ((size_t)b * RC + ch0) * SKIP_SZ + (c - (TFULL - SKIP_SZ));
#pragma unroll
                for (int r = 0; r < 4; ++r) sp[(size_t)r * SKIP_SZ] = sk[r];
            }
        }
    }
}

// ---------------------------------------------------------------------------
// Fused pair (blk, blk+1), templated <D1,D2,H>; 1024 thr = 16 waves, frag
// ranges split across colhalf at compile time. Math identical to R12.
// ---------------------------------------------------------------------------
template<int D1, int D2, int H>
__global__ __launch_bounds__(1024, 8) void wn_pair(
    const unsigned short* __restrict__ curh, const unsigned short* __restrict__ curl,
    unsigned short* __restrict__ nxth, unsigned short* __restrict__ nxtl,
    const unsigned short* __restrict__ Wdh, const unsigned short* __restrict__ Wdl,
    const unsigned short* __restrict__ Wrh, const unsigned short* __restrict__ Wrl,
    const unsigned short* __restrict__ Wsh, const unsigned short* __restrict__ Wsl,
    const float* __restrict__ br_all, const float* __restrict__ bs_all,
    float* __restrict__ out, int blk, int col0)
{
    __shared__ char lds[LDSB];

    constexpr int NF1 = (64 + H) >> 4;       // 5 (H=16) or 6 (H=32)
    constexpr int NHALO = H >> 4;
    constexpr int NF1A = (NF1 + 1) >> 1;     // frags for colhalf 0 (=3)
    constexpr int O0 = STGH - H - D1;
    constexpr int O1 = STGH - H;
    constexpr int P0 = H - D2;
    constexpr int P1 = H;

    const int tid   = threadIdx.x;
    const int lane  = tid & 63;
    const int wave  = tid >> 6;          // 0..15
    const int mf    = wave >> 1;
    const int chalf = wave & 1;
    const int l15   = lane & 15, lq = lane >> 4;
    const int u     = blockIdx.x;
    const int b     = u & 3;
    const int t0    = col0 + (u >> 2) * 64;
    const size_t xbase = (size_t)b * TFULL * RC;
    const int ch0   = mf * 16 + lq * 4;
    const int nt    = TFULL - t0 < 64 ? TFULL - t0 : 64;

    const unsigned short* Wd1h = Wdh + (size_t)blk * 32768;
    const unsigned short* Wd1l = Wdl + (size_t)blk * 32768;
    const unsigned short* Wd2h = Wd1h + 32768;
    const unsigned short* Wd2l = Wd1l + 32768;
    const unsigned short* Wr1h = Wrh + (size_t)blk * 16384;
    const unsigned short* Wr1l = Wrl + (size_t)blk * 16384;
    const unsigned short* Wr2h = Wr1h + 16384;
    const unsigned short* Wr2l = Wr1l + 16384;
    const unsigned short* Ws1h = Wsh + (size_t)blk * 16384;
    const unsigned short* Ws1l = Wsl + (size_t)blk * 16384;
    const unsigned short* Ws2h = Ws1h + 16384;
    const unsigned short* Ws2l = Ws1l + 16384;
    const float* br1 = br_all + (size_t)blk * RC;
    const float* bs1 = bs_all + (size_t)blk * RC;
    const float* br2 = br1 + RC;
    const float* bs2 = bs1 + RC;
    float* skip1 = out + (size_t)blk * BATCH * RC * SKIP_SZ;
    float* skip2 = skip1 + (size_t)BATCH * RC * SKIP_SZ;

    // ---- stage X hi: plane cols [0,112) = global [t0-48, t0+64)
#pragma unroll
    for (int r = 0; r < 2; ++r) {
        const int j = wave * 2 + r;      // 0..31
        if (j < 28) {
            const int c4   = j * 4;
            const int pcol = c4 + lq;
            const int chs  = l15 ^ (pcol & 7);
            int g = t0 - STGH + pcol;
            g = g < 0 ? 0 : (g > TFULL - 1 ? TFULL - 1 : g);
            const unsigned short* gsrc = curh + xbase + (size_t)g * RC + chs * 8;
            __builtin_amdgcn_global_load_lds(GLB1(gsrc), LDS3(lds + RX + c4 * 256), 16, 0, 0);
        }
    }
    __syncthreads();   // B1

    // ---- block blk dilated conv; this wave handles frags F = chalf*NF1A + nf
    f32x4 a1[NF1A];
#pragma unroll
    for (int nf = 0; nf < NF1A; ++nf) a1[nf] = (f32x4){0.f, 0.f, 0.f, 0.f};
#pragma unroll
    for (int ks = 0; ks < 8; ++ks) {
        const int tap = ks >> 2;
        const int kk  = ks & 3;
        const size_t wi = ((size_t)(ks * 8 + mf) * 64 + lane) * 8;
        bf16x8 ah = *(const bf16x8*)(Wd1h + wi);
        bf16x8 al = *(const bf16x8*)(Wd1l + wi);
#pragma unroll
        for (int nf = 0; nf < NF1A; ++nf) {
            const int F = chalf * NF1A + nf;
            if (F < NF1) {
                const int pc  = F * 16 + l15 + (tap ? O1 : O0);
                const int byo = pc * 256 + ((kk * 64 + lq * 16) ^ ((pc & 7) << 4));
                bf16x8 bh = *(const bf16x8*)(lds + RX + byo);
                a1[nf] = __builtin_amdgcn_mfma_f32_16x16x32_bf16(ah, bh, a1[nf], 0, 0, 0);
                a1[nf] = __builtin_amdgcn_mfma_f32_16x16x32_bf16(al, bh, a1[nf], 0, 0, 0);
            }
        }
    }

    // ---- gate_i -> RG
#pragma unroll
    for (int nf = 0; nf < NF1A; ++nf) {
        const int F = chalf * NF1A + nf;
        if (F < NF1) {
            const int gc  = F * 16 + l15;
            const int byo = gc * 256 + ((ch0 * 2) ^ ((gc & 7) << 4));
            bf16x4 hv;
#pragma unroll
            for (int r = 0; r < 4; ++r)
                hv[r] = (short)f2bf(gatef(a1[nf][r]));
            *(bf16x4*)(lds + RG + byo) = hv;
        }
    }
    __syncthreads();   // B2

    // ---- res/skip_i
    f32x4 r1[NF1A], s1[NF1A];
#pragma unroll
    for (int nf = 0; nf < NF1A; ++nf) {
        r1[nf] = (f32x4){0.f, 0.f, 0.f, 0.f};
        s1[nf] = (f32x4){0.f, 0.f, 0.f, 0.f};
    }
#pragma unroll
    for (int ks = 0; ks < 4; ++ks) {
        const size_t wi = ((size_t)(ks * 8 + mf) * 64 + lane) * 8;
        bf16x8 rh = *(const bf16x8*)(Wr1h + wi);
        bf16x8 rl = *(const bf16x8*)(Wr1l + wi);
        bf16x8 sh = *(const bf16x8*)(Ws1h + wi);
        bf16x8 sl = *(const bf16x8*)(Ws1l + wi);
#pragma unroll
        for (int nf = 0; nf < NF1A; ++nf) {
            const int F = chalf * NF1A + nf;
            if (F < NF1) {
                const int gc  = F * 16 + l15;
                const int byo = gc * 256 + ((ks * 64 + lq * 16) ^ ((gc & 7) << 4));
                bf16x8 g = *(const bf16x8*)(lds + RG + byo);
                r1[nf] = __builtin_amdgcn_mfma_f32_16x16x32_bf16(rh, g, r1[nf], 0, 0, 0);
                r1[nf] = __builtin_amdgcn_mfma_f32_16x16x32_bf16(rl, g, r1[nf], 0, 0, 0);
                s1[nf] = __builtin_amdgcn_mfma_f32_16x16x32_bf16(sh, g, s1[nf], 0, 0, 0);
                s1[nf] = __builtin_amdgcn_mfma_f32_16x16x32_bf16(sl, g, s1[nf], 0, 0, 0);
            }
        }
    }
    __syncthreads();   // B3 (RG reads done; y_lo will overwrite it)

    // ---- epilogue_i: y_hi -> RY (all frags), y_lo -> RG + skip (core frags)
    {
        const float4 br1v = *(const float4*)(br1 + ch0);
        const float4 bs1v = *(const float4*)(bs1 + ch0);
#pragma unroll
        for (int nf = 0; nf < NF1A; ++nf) {
            const int F = chalf * NF1A + nf;
            if (F < NF1) {
                const int yc = F * 16 + l15;
                const int c  = t0 - H + yc;
                const int pcx = yc + O1;
                bf16x4 xh = *(const bf16x4*)(lds + RX + pcx * 256 + ((ch0 * 2) ^ ((pcx & 7) << 4)));
                int cg = c < 0 ? 0 : (c > TFULL - 1 ? TFULL - 1 : c);
                bf16x4 xl = *(const bf16x4*)(curl + xbase + (size_t)cg * RC + ch0);
                bf16x4 yh4, yl4;
                float sk[4];
#pragma unroll
                for (int r = 0; r < 4; ++r) {
                    float xe = bf2f((unsigned short)xh[r]) + bf2f((unsigned short)xl[r]);
                    float y  = r1[nf][r] + ((const float*)&br1v)[r] + xe;
                    unsigned short h = f2bf(y);
                    yh4[r] = (short)h;
                    yl4[r] = (short)f2bf(y - bf2f(h));
                    sk[r]  = s1[nf][r] + ((const float*)&bs1v)[r];
                }
                *(bf16x4*)(lds + RY + yc * 256 + ((ch0 * 2) ^ ((yc & 7) << 4))) = yh4;
                if (F >= NHALO) {
                    const int lc = yc - H;
                    *(bf16x4*)(lds + RG + lc * 256 + ((ch0 * 2) ^ ((lc & 7) << 4))) = yl4;
                    if (lc < nt && c >= TFULL - SKIP_SZ) {
                        float* sp = skip1 + ((size_t)b * RC + ch0) * SKIP_SZ + (c - (TFULL - SKIP_SZ));
#pragma unroll
                        for (int r = 0; r < 4; ++r) sp[(size_t)r * SKIP_SZ] = sk[r];
                    }
                }
            }
        }
    }
    __syncthreads();   // B4 (y planes ready; RX dead)

    // ---- block blk+1 dilated over 4 core frags (2 per colhalf), B from RY
    f32x4 a2[2];
#pragma unroll
    for (int nf = 0; nf < 2; ++nf) a2[nf] = (f32x4){0.f, 0.f, 0.f, 0.f};
#pragma unroll
    for (int ks = 0; ks < 8; ++ks) {
        const int tap = ks >> 2;
        const int kk  = ks & 3;
        const size_t wi = ((size_t)(ks * 8 + mf) * 64 + lane) * 8;
        bf16x8 ah = *(const bf16x8*)(Wd2h + wi);
        bf16x8 al = *(const bf16x8*)(Wd2l + wi);
#pragma unroll
        for (int nf = 0; nf < 2; ++nf) {
            const int yi  = (chalf * 2 + nf) * 16 + l15 + (tap ? P1 : P0);
            const int byo = yi * 256 + ((kk * 64 + lq * 16) ^ ((yi & 7) << 4));
            bf16x8 bh = *(const bf16x8*)(lds + RY + byo);
            a2[nf] = __builtin_amdgcn_mfma_f32_16x16x32_bf16(ah, bh, a2[nf], 0, 0, 0);
            a2[nf] = __builtin_amdgcn_mfma_f32_16x16x32_bf16(al, bh, a2[nf], 0, 0, 0);
        }
    }

    // ---- gate_{i+1} -> RX (cols 0..63)
#pragma unroll
    for (int nf = 0; nf < 2; ++nf) {
        const int gc  = (chalf * 2 + nf) * 16 + l15;
        const int byo = gc * 256 + ((ch0 * 2) ^ ((gc & 7) << 4));
        bf16x4 hv;
#pragma unroll
        for (int r = 0; r < 4; ++r)
            hv[r] = (short)f2bf(gatef(a2[nf][r]));
        *(bf16x4*)(lds + RX + byo) = hv;
    }
    __syncthreads();   // B5

    // ---- res/skip_{i+1}
    f32x4 r2[2], s2[2];
#pragma unroll
    for (int nf = 0; nf < 2; ++nf) {
        r2[nf] = (f32x4){0.f, 0.f, 0.f, 0.f};
        s2[nf] = (f32x4){0.f, 0.f, 0.f, 0.f};
    }
#pragma unroll
    for (int ks = 0; ks < 4; ++ks) {
        const size_t wi = ((size_t)(ks * 8 + mf) * 64 + lane) * 8;
        bf16x8 rh = *(const bf16x8*)(Wr2h + wi);
        bf16x8 rl = *(const bf16x8*)(Wr2l + wi);
        bf16x8 sh = *(const bf16x8*)(Ws2h + wi);
        bf16x8 sl = *(const bf16x8*)(Ws2l + wi);
#pragma unroll
        for (int nf = 0; nf < 2; ++nf) {
            const int gc  = (chalf * 2 + nf) * 16 + l15;
            const int byo = gc * 256 + ((ks * 64 + lq * 16) ^ ((gc & 7) << 4));
            bf16x8 g = *(const bf16x8*)(lds + RX + byo);
            r2[nf] = __builtin_amdgcn_mfma_f32_16x16x32_bf16(rh, g, r2[nf], 0, 0, 0);
            r2[nf] = __builtin_amdgcn_mfma_f32_16x16x32_bf16(rl, g, r2[nf], 0, 0, 0);
            s2[nf] = __builtin_amdgcn_mfma_f32_16x16x32_bf16(sh, g, s2[nf], 0, 0, 0);
            s2[nf] = __builtin_amdgcn_mfma_f32_16x16x32_bf16(sl, g, s2[nf], 0, 0, 0);
        }
    }

    // ---- epilogue_{i+1}: y = r2 + br2 + y_i exact (RY+RG); store
    {
        const float4 br2v = *(const float4*)(br2 + ch0);
        const float4 bs2v = *(const float4*)(bs2 + ch0);
#pragma unroll
        for (int nf = 0; nf < 2; ++nf) {
            const int lc = (chalf * 2 + nf) * 16 + l15;
            if (lc < nt) {
                const int c  = t0 + lc;
                const int yc = lc + H;
                bf16x4 yh = *(const bf16x4*)(lds + RY + yc * 256 + ((ch0 * 2) ^ ((yc & 7) << 4)));
                bf16x4 yl = *(const bf16x4*)(lds + RG + lc * 256 + ((ch0 * 2) ^ ((lc & 7) << 4)));
                bf16x4 oh, ol;
                float sk[4];
#pragma unroll
                for (int r = 0; r < 4; ++r) {
                    float ye = bf2f((unsigned short)yh[r]) + bf2f((unsigned short)yl[r]);
                    float y  = r2[nf][r] + ((const float*)&br2v)[r] + ye;
                    unsigned short h = f2bf(y);
                    oh[r] = (short)h;
                    ol[r] = (short)f2bf(y - bf2f(h));
                    sk[r] = s2[nf][r] + ((const float*)&bs2v)[r];
                }
                const size_t off = xbase + (size_t)c * RC + ch0;
                *(bf16x4*)(nxth + off) = oh;
                *(bf16x4*)(nxtl + off) = ol;
                if (c >= TFULL - SKIP_SZ) {
                    float* sp = skip2 + ((size_t)b * RC + ch0) * SKIP_SZ + (c - (TFULL - SKIP_SZ));
#pragma unroll
                    for (int r = 0; r < 4; ++r) sp[(size_t)r * SKIP_SZ] = sk[r];
                }
            }
        }
    }
}

extern "C" void kernel_launch(void* const* d_in, const int* in_sizes, int n_in,
                              void* d_out, int out_size, void* d_ws, size_t ws_size,
                              hipStream_t stream) {
    const float* x  = (const float*)d_in[0];
    const float* Wd = (const float*)d_in[1];
    const float* Wr = (const float*)d_in[2];
    const float* br = (const float*)d_in[3];
    const float* Ws = (const float*)d_in[4];
    const float* bs = (const float*)d_in[5];
    float* out = (float*)d_out;

    const size_t SLOT = (size_t)BATCH * TFULL * RC;
    unsigned short* Xs0h = (unsigned short*)d_ws;
    unsigned short* Xs0l = Xs0h + SLOT;
    unsigned short* Xs1h = Xs0l + SLOT;
    unsigned short* Xs1l = Xs1h + SLOT;
    unsigned short* Wdh = Xs1l + SLOT;
    unsigned short* Wdl = Wdh + (size_t)NB * 32768;
    unsigned short* Wrh = Wdl + (size_t)NB * 32768;
    unsigned short* Wrl = Wrh + (size_t)NB * 16384;
    unsigned short* Wsh = Wrl + (size_t)NB * 16384;
    unsigned short* Wsl = Wsh + (size_t)NB * 16384;

    xpose_split<<<dim3(TFULL / 64, RC / 32, BATCH), 256, 0, stream>>>(x, Xs0h, Xs0l);
    {
        int total = NB * 4096 + 2 * NB * 2048;
        wpack<<<dim3((total + 255) / 256), 256, 0, stream>>>(Wd, Wr, Ws, Wdh, Wdl, Wrh, Wrl, Wsh, Wsl);
    }

    int L = TFULL;
    int pp = 0;
    for (int s = 0; s < 4; ++s) {
        // fused pairs: (1,2), (4,8), (16,32)
        for (int p = 0; p < 3; ++p) {
            const int i  = s * 10 + p * 2;
            const int d1 = (p == 0) ? 1 : (p == 1) ? 4 : 16;
            const int d2 = d1 * 2;
            const int Lout = L - d1 - d2;
            const int col0 = TFULL - Lout;
            const int units = ((Lout + 63) >> 6) * BATCH;
            unsigned short* curh = pp ? Xs1h : Xs0h;
            unsigned short* curl = pp ? Xs1l : Xs0l;
            unsigned short* nxth = pp ? Xs0h : Xs1h;
            unsigned short* nxtl = pp ? Xs0l : Xs1l;
            if (p == 0)
                wn_pair<1, 2, 16><<<dim3(units), dim3(1024), 0, stream>>>(
                    curh, curl, nxth, nxtl, Wdh, Wdl, Wrh, Wrl, Wsh, Wsl,
                    br, bs, out, i, col0);
            else if (p == 1)
                wn_pair<4, 8, 16><<<dim3(units), dim3(1024), 0, stream>>>(
                    curh, curl, nxth, nxtl, Wdh, Wdl, Wrh, Wrl, Wsh, Wsl,
                    br, bs, out, i, col0);
            else
                wn_pair<16, 32, 32><<<dim3(units), dim3(1024), 0, stream>>>(
                    curh, curl, nxth, nxtl, Wdh, Wdl, Wrh, Wrl, Wsh, Wsl,
                    br, bs, out, i, col0);
            pp ^= 1;
            L = Lout;
        }
        // singles: d = 64, 128, 256, 512
        for (int q = 6; q < 10; ++q) {
            const int i = s * 10 + q;
            const int d = 1 << q;
            const int Lout = L - d;
            const int col0 = TFULL - Lout;
            const int units = ((Lout + 63) >> 6) * BATCH;
            unsigned short* curh = pp ? Xs1h : Xs0h;
            unsigned short* curl = pp ? Xs1l : Xs0l;
            unsigned short* nxth = pp ? Xs0h : Xs1h;
            unsigned short* nxtl = pp ? Xs0l : Xs1l;
            wn_step<<<dim3(units), dim3(1024), 0, stream>>>(
                curh, curl, nxth, nxtl,
                Wdh + (size_t)i * 32768, Wdl + (size_t)i * 32768,
                Wrh + (size_t)i * 16384, Wrl + (size_t)i * 16384,
                Wsh + (size_t)i * 16384, Wsl + (size_t)i * 16384,
                br + (size_t)i * RC, bs + (size_t)i * RC,
                out + (size_t)i * BATCH * RC * SKIP_SZ, d, col0);
            pp ^= 1;
            L = Lout;
        }
    }
}

// Round 14
// 648.953 us; speedup vs baseline: 1.2438x; 1.2438x over previous
//
#include <hip/hip_runtime.h>

typedef __attribute__((ext_vector_type(8))) short bf16x8;
typedef __attribute__((ext_vector_type(4))) short bf16x4;
typedef __attribute__((ext_vector_type(4))) float f32x4;

#define TFULL 8192
#define RC 128
#define NB 40
#define BATCH 4
#define SKIP_SZ 4096

#define LDS3(p) ((__attribute__((address_space(3))) void*)(p))
#define GLB1(p) ((const __attribute__((address_space(1))) void*)(p))

// ---- single-block kernel LDS (R12 proven layout) ----
#define XPLANE 16384
#define LDS_BYTES (3 * XPLANE)   // 48 KB -> 2 WG/CU

__device__ __forceinline__ unsigned short f2bf(float f) {
    unsigned u = __builtin_bit_cast(unsigned, f);
    u += 0x7FFFu + ((u >> 16) & 1u);          // round-to-nearest-even
    return (unsigned short)(u >> 16);
}
__device__ __forceinline__ float bf2f(unsigned short h) {
    unsigned u = ((unsigned)h) << 16;
    return __builtin_bit_cast(float, u);
}
// tanh(y)*sigmoid(y) via one fast exp (clamped; saturation exact).
__device__ __forceinline__ float gatef(float y) {
    float yc = fminf(fmaxf(y, -30.f), 30.f);
    float e  = __expf(-yc);
    float e2 = e * e;
    return (1.f - e2) * __builtin_amdgcn_rcpf(1.f + e2)
                      * __builtin_amdgcn_rcpf(1.f + e);
}

// ---------------------------------------------------------------------------
// Pre-pass 1: transpose x [B][128ch][8192col] fp32 -> hi/lo bf16 [B][col][ch]
// ---------------------------------------------------------------------------
__global__ __launch_bounds__(256) void xpose_split(
    const float* __restrict__ x,
    unsigned short* __restrict__ Xh, unsigned short* __restrict__ Xl)
{
    __shared__ float t[32][65];
    const int col0 = blockIdx.x * 64;
    const int ch0  = blockIdx.y * 32;
    const int b    = blockIdx.z;
    const int tid  = threadIdx.x;
    const int tx = tid & 63, ty = tid >> 6;
#pragma unroll
    for (int i = 0; i < 8; ++i) {
        int ch = ty + i * 4;
        t[ch][tx] = x[((size_t)(b * RC + ch0 + ch)) * TFULL + col0 + tx];
    }
    __syncthreads();
    for (int idx = tid; idx < 64 * 32; idx += 256) {
        int col = idx >> 5, ch = idx & 31;
        float v = t[ch][col];
        unsigned short h = f2bf(v);
        unsigned short l = f2bf(v - bf2f(h));
        size_t off = ((size_t)(b * TFULL + col0 + col)) * RC + ch0 + ch;
        Xh[off] = h;
        Xl[off] = l;
    }
}

// ---------------------------------------------------------------------------
// Pre-pass 2: pack weights into per-MFMA-A-fragment layout, hi/lo bf16.
// A[m][k]: lane l holds rows m=16*mf+(l&15), k = 32*ks + (l>>4)*8 + j.
// Dilated k = tap*128 + i. Dst flat: ((blk*KS*8 + ks*8 + mf)*64 + lane)*8 + j.
// ---------------------------------------------------------------------------
__global__ __launch_bounds__(256) void wpack(
    const float* __restrict__ Wd, const float* __restrict__ Wr, const float* __restrict__ Ws,
    unsigned short* __restrict__ Wdh, unsigned short* __restrict__ Wdl,
    unsigned short* __restrict__ Wrh, unsigned short* __restrict__ Wrl,
    unsigned short* __restrict__ Wsh, unsigned short* __restrict__ Wsl)
{
    const int Nd = NB * 4096;
    const int Nr = NB * 2048;
    int id = blockIdx.x * 256 + threadIdx.x;
    const float* src;
    unsigned short *dh, *dl;
    int blk, rloc;
    bool dil = false;
    size_t dbase;
    if (id < Nd)               { dil = true; blk = id >> 12; rloc = id & 4095; dh = Wdh; dl = Wdl; src = Wd; dbase = (size_t)id * 8; }
    else if (id < Nd + Nr)     { int t = id - Nd;      blk = t >> 11; rloc = t & 2047; dh = Wrh; dl = Wrl; src = Wr; dbase = (size_t)t * 8; }
    else if (id < Nd + 2 * Nr) { int t = id - Nd - Nr; blk = t >> 11; rloc = t & 2047; dh = Wsh; dl = Wsl; src = Ws; dbase = (size_t)t * 8; }
    else return;
    const int ks = rloc >> 9, mf = (rloc >> 6) & 7, lane = rloc & 63;
    const int m = mf * 16 + (lane & 15);
    const int kb = ks * 32 + ((lane >> 4) << 3);
    bf16x8 hv, lv;
#pragma unroll
    for (int j = 0; j < 8; ++j) {
        int k = kb + j;
        float w;
        if (dil) {
            int tap = k >> 7, i = k & 127;
            w = src[((((size_t)blk * 128 + m) * 128) + i) * 2 + tap];
        } else {
            w = src[(((size_t)blk * 128 + m) * 128) + k];
        }
        unsigned short h = f2bf(w);
        hv[j] = (short)h;
        lv[j] = (short)f2bf(w - bf2f(h));
    }
    *(bf16x8*)(dh + dbase) = hv;
    *(bf16x8*)(dl + dbase) = lv;
}

// ---------------------------------------------------------------------------
// Single-block step (R10/R12 proven): 512 thr, wave = mf slot x 64 cols,
// 2-product weights x bf16 X, gated bf16, stream exact hi/lo.
// ---------------------------------------------------------------------------
__global__ __launch_bounds__(512, 4) void wn_step(
    const unsigned short* __restrict__ curh, const unsigned short* __restrict__ curl,
    unsigned short* __restrict__ nxth, unsigned short* __restrict__ nxtl,
    const unsigned short* __restrict__ Wdh_i, const unsigned short* __restrict__ Wdl_i,
    const unsigned short* __restrict__ Wrh_i, const unsigned short* __restrict__ Wrl_i,
    const unsigned short* __restrict__ Wsh_i, const unsigned short* __restrict__ Wsl_i,
    const float* __restrict__ br, const float* __restrict__ bs,
    float* __restrict__ skip, int d, int col0)
{
    __shared__ char lds[LDS_BYTES];

    const int tid  = threadIdx.x;
    const int lane = tid & 63;
    const int wave = tid >> 6;
    const int l15  = lane & 15, lq = lane >> 4;
    const int u    = blockIdx.x;
    const int b    = u & 3;
    const int tile0 = col0 + (u >> 2) * 64;
    const size_t xbase = (size_t)b * TFULL * RC;

#pragma unroll
    for (int r = 0; r < 4; ++r) {
        const int j   = wave * 4 + r;
        const int tap = j >> 4;
        const int c4  = (j & 15) * 4;
        const int col = c4 + lq;
        const int chs = l15 ^ (col & 7);
        int cg_ = tile0 + col;
        cg_ = cg_ > TFULL - 1 ? TFULL - 1 : cg_;
        if (!tap) cg_ -= d;
        const unsigned short* gsrc = curh + xbase + (size_t)cg_ * RC + chs * 8;
        char* ldst = lds + tap * XPLANE + c4 * 256;
        __builtin_amdgcn_global_load_lds(GLB1(gsrc), LDS3(ldst), 16, 0, 0);
    }
    __syncthreads();

    f32x4 acc[4];
#pragma unroll
    for (int nf = 0; nf < 4; ++nf) acc[nf] = (f32x4){0.f, 0.f, 0.f, 0.f};

#pragma unroll
    for (int ks = 0; ks < 8; ++ks) {
        const int tap = ks >> 2;
        const int kk  = ks & 3;
        const size_t wi = ((size_t)(ks * 8 + wave) * 64 + lane) * 8;
        bf16x8 ah = *(const bf16x8*)(Wdh_i + wi);
        bf16x8 al = *(const bf16x8*)(Wdl_i + wi);
#pragma unroll
        for (int nf = 0; nf < 4; ++nf) {
            const int col = nf * 16 + l15;
            const int byo = (kk * 64 + lq * 16) ^ ((col & 7) << 4);
            bf16x8 bh = *(const bf16x8*)(lds + tap * XPLANE + col * 256 + byo);
            acc[nf] = __builtin_amdgcn_mfma_f32_16x16x32_bf16(ah, bh, acc[nf], 0, 0, 0);
            acc[nf] = __builtin_amdgcn_mfma_f32_16x16x32_bf16(al, bh, acc[nf], 0, 0, 0);
        }
    }

    const int ch0 = wave * 16 + lq * 4;
#pragma unroll
    for (int nf = 0; nf < 4; ++nf) {
        const int n   = nf * 16 + l15;
        const int byo = (ch0 * 2) ^ ((n & 7) << 4);
        bf16x4 hv;
#pragma unroll
        for (int r = 0; r < 4; ++r)
            hv[r] = (short)f2bf(gatef(acc[nf][r]));
        *(bf16x4*)(lds + 2 * XPLANE + n * 256 + byo) = hv;
    }
    __syncthreads();

    f32x4 accr[4], accs[4];
#pragma unroll
    for (int nf = 0; nf < 4; ++nf) {
        accr[nf] = (f32x4){0.f, 0.f, 0.f, 0.f};
        accs[nf] = (f32x4){0.f, 0.f, 0.f, 0.f};
    }
#pragma unroll
    for (int ks = 0; ks < 4; ++ks) {
        const size_t wi = ((size_t)(ks * 8 + wave) * 64 + lane) * 8;
        bf16x8 rh = *(const bf16x8*)(Wrh_i + wi);
        bf16x8 rl = *(const bf16x8*)(Wrl_i + wi);
        bf16x8 sh = *(const bf16x8*)(Wsh_i + wi);
        bf16x8 sl = *(const bf16x8*)(Wsl_i + wi);
#pragma unroll
        for (int nf = 0; nf < 4; ++nf) {
            const int col = nf * 16 + l15;
            const int byo = (ks * 64 + lq * 16) ^ ((col & 7) << 4);
            bf16x8 g = *(const bf16x8*)(lds + 2 * XPLANE + col * 256 + byo);
            accr[nf] = __builtin_amdgcn_mfma_f32_16x16x32_bf16(rh, g, accr[nf], 0, 0, 0);
            accr[nf] = __builtin_amdgcn_mfma_f32_16x16x32_bf16(rl, g, accr[nf], 0, 0, 0);
            accs[nf] = __builtin_amdgcn_mfma_f32_16x16x32_bf16(sh, g, accs[nf], 0, 0, 0);
            accs[nf] = __builtin_amdgcn_mfma_f32_16x16x32_bf16(sl, g, accs[nf], 0, 0, 0);
        }
    }

    const int nt = TFULL - tile0 < 64 ? TFULL - tile0 : 64;
    const float4 brv = *(const float4*)(br + ch0);
    const float4 bsv = *(const float4*)(bs + ch0);
#pragma unroll
    for (int nf = 0; nf < 4; ++nf) {
        const int n = nf * 16 + l15;
        if (n < nt) {
            const int c = tile0 + n;
            const int byo = (ch0 * 2) ^ ((n & 7) << 4);
            bf16x4 ih = *(const bf16x4*)(lds + XPLANE + n * 256 + byo);
            const size_t off = xbase + (size_t)c * RC + ch0;
            bf16x4 il = *(const bf16x4*)(curl + off);
            bf16x4 oh, ol;
            float sk[4];
#pragma unroll
            for (int r = 0; r < 4; ++r) {
                float inv = bf2f((unsigned short)ih[r]) + bf2f((unsigned short)il[r]);
                float rv = accr[nf][r] + ((const float*)&brv)[r] + inv;
                unsigned short h = f2bf(rv);
                oh[r] = (short)h;
                ol[r] = (short)f2bf(rv - bf2f(h));
                sk[r] = accs[nf][r] + ((const float*)&bsv)[r];
            }
            *(bf16x4*)(nxth + off) = oh;
            *(bf16x4*)(nxtl + off) = ol;
            if (c >= TFULL - SKIP_SZ) {
                float* sp = skip + ((size_t)b * RC + ch0) * SKIP_SZ + (c - (TFULL - SKIP_SZ));
#pragma unroll
                for (int r = 0; r < 4; ++r) sp[(size_t)r * SKIP_SZ] = sk[r];
            }
        }
    }
}

// ---------------------------------------------------------------------------
// Fused TRIPLE (blk, blk+1, blk+2), templated <D1,D2,D3,STGHB,H1,H2,KEEPY1L>.
// Core = [t0,t0+64). Block1 over 64+H1 cols, block2 over 64+H2, block3 core.
// y1 exact (hi+lo) iff KEEPY1L; y2 handed to block3 as bf16-hi only (one
// extra stream rounding per triple; two when !KEEPY1L).
// Regions: R_X: X-hi -> g2 -> y2h | R_B: g1 -> y1h -> g3 | R_C: y1l (opt).
// ---------------------------------------------------------------------------
template<int D1, int D2, int D3, int STGHB, int H1, int H2, bool KEEPY1L>
__global__ __launch_bounds__(512, 4) void wn_triple(
    const unsigned short* __restrict__ curh, const unsigned short* __restrict__ curl,
    unsigned short* __restrict__ nxth, unsigned short* __restrict__ nxtl,
    const unsigned short* __restrict__ Wdh, const unsigned short* __restrict__ Wdl,
    const unsigned short* __restrict__ Wrh, const unsigned short* __restrict__ Wrl,
    const unsigned short* __restrict__ Wsh, const unsigned short* __restrict__ Wsl,
    const float* __restrict__ br_all, const float* __restrict__ bs_all,
    float* __restrict__ out, int blk, int col0)
{
    constexpr int NF1 = (64 + H1) >> 4;
    constexpr int NF2 = (64 + H2) >> 4;
    constexpr int RXC = 64 + STGHB;
    constexpr int R_B = RXC * 256;
    constexpr int R_C = R_B + NF1 * 16 * 256;
    constexpr int LDST = R_C + (KEEPY1L ? NF2 * 16 * 256 : 0);
    constexpr int O0 = STGHB - H1 - D1, O1 = STGHB - H1;   // conv1 taps in X
    constexpr int Q0 = H1 - H2 - D2,   Q1 = H1 - H2;       // conv2 taps in y1h
    constexpr int P0 = H2 - D3,        P1 = H2;            // conv3 taps in y2h
    constexpr int FH1 = H1 >> 4;                           // core frag start, blk1
    constexpr int FH2 = H2 >> 4;                           // core frag start, blk2
    constexpr int FQ  = (H1 - H2) >> 4;                    // y1l frag start

    __shared__ char lds[LDST];

    const int tid  = threadIdx.x;
    const int lane = tid & 63;
    const int wave = tid >> 6;
    const int l15  = lane & 15, lq = lane >> 4;
    const int u    = blockIdx.x;
    const int b    = u & 3;
    const int t0   = col0 + (u >> 2) * 64;
    const size_t xbase = (size_t)b * TFULL * RC;
    const int ch0  = wave * 16 + lq * 4;
    const int nt   = TFULL - t0 < 64 ? TFULL - t0 : 64;

    const unsigned short* Wd1h = Wdh + (size_t)blk * 32768;
    const unsigned short* Wd1l = Wdl + (size_t)blk * 32768;
    const unsigned short* Wd2h = Wd1h + 32768;
    const unsigned short* Wd2l = Wd1l + 32768;
    const unsigned short* Wd3h = Wd2h + 32768;
    const unsigned short* Wd3l = Wd2l + 32768;
    const unsigned short* Wr1h = Wrh + (size_t)blk * 16384;
    const unsigned short* Wr1l = Wrl + (size_t)blk * 16384;
    const unsigned short* Wr2h = Wr1h + 16384;
    const unsigned short* Wr2l = Wr1l + 16384;
    const unsigned short* Wr3h = Wr2h + 16384;
    const unsigned short* Wr3l = Wr2l + 16384;
    const unsigned short* Ws1h = Wsh + (size_t)blk * 16384;
    const unsigned short* Ws1l = Wsl + (size_t)blk * 16384;
    const unsigned short* Ws2h = Ws1h + 16384;
    const unsigned short* Ws2l = Ws1l + 16384;
    const unsigned short* Ws3h = Ws2h + 16384;
    const unsigned short* Ws3l = Ws2l + 16384;
    const float* br1 = br_all + (size_t)blk * RC;
    const float* bs1 = bs_all + (size_t)blk * RC;
    const float* br2 = br1 + RC;
    const float* bs2 = bs1 + RC;
    const float* br3 = br2 + RC;
    const float* bs3 = bs2 + RC;
    float* skip1 = out + (size_t)blk * BATCH * RC * SKIP_SZ;
    float* skip2 = skip1 + (size_t)BATCH * RC * SKIP_SZ;
    float* skip3 = skip2 + (size_t)BATCH * RC * SKIP_SZ;

    // ---- stage X hi: cols [0,RXC) = global [t0-STGHB, t0+64)
#pragma unroll
    for (int r = 0; r < 4; ++r) {
        const int j = wave * 4 + r;
        if (j < RXC / 4) {
            const int c4   = j * 4;
            const int pcol = c4 + lq;
            const int chs  = l15 ^ (pcol & 7);
            int g = t0 - STGHB + pcol;
            g = g < 0 ? 0 : (g > TFULL - 1 ? TFULL - 1 : g);
            const unsigned short* gsrc = curh + xbase + (size_t)g * RC + chs * 8;
            __builtin_amdgcn_global_load_lds(GLB1(gsrc), LDS3(lds + c4 * 256), 16, 0, 0);
        }
    }
    __syncthreads();   // B1

    // ======== sub-block 1 ========
    f32x4 a1[NF1];
#pragma unroll
    for (int nf = 0; nf < NF1; ++nf) a1[nf] = (f32x4){0.f, 0.f, 0.f, 0.f};
#pragma unroll
    for (int ks = 0; ks < 8; ++ks) {
        const int tap = ks >> 2;
        const int kk  = ks & 3;
        const size_t wi = ((size_t)(ks * 8 + wave) * 64 + lane) * 8;
        bf16x8 ah = *(const bf16x8*)(Wd1h + wi);
        bf16x8 al = *(const bf16x8*)(Wd1l + wi);
#pragma unroll
        for (int nf = 0; nf < NF1; ++nf) {
            const int pc  = nf * 16 + l15 + (tap ? O1 : O0);
            const int byo = pc * 256 + ((kk * 64 + lq * 16) ^ ((pc & 7) << 4));
            bf16x8 bh = *(const bf16x8*)(lds + byo);
            a1[nf] = __builtin_amdgcn_mfma_f32_16x16x32_bf16(ah, bh, a1[nf], 0, 0, 0);
            a1[nf] = __builtin_amdgcn_mfma_f32_16x16x32_bf16(al, bh, a1[nf], 0, 0, 0);
        }
    }
    // gate1 -> R_B
#pragma unroll
    for (int nf = 0; nf < NF1; ++nf) {
        const int gc  = nf * 16 + l15;
        const int byo = gc * 256 + ((ch0 * 2) ^ ((gc & 7) << 4));
        bf16x4 hv;
#pragma unroll
        for (int r = 0; r < 4; ++r)
            hv[r] = (short)f2bf(gatef(a1[nf][r]));
        *(bf16x4*)(lds + R_B + byo) = hv;
    }
    __syncthreads();   // B2

    f32x4 r1[NF1], s1[NF1];
#pragma unroll
    for (int nf = 0; nf < NF1; ++nf) {
        r1[nf] = (f32x4){0.f, 0.f, 0.f, 0.f};
        s1[nf] = (f32x4){0.f, 0.f, 0.f, 0.f};
    }
#pragma unroll
    for (int ks = 0; ks < 4; ++ks) {
        const size_t wi = ((size_t)(ks * 8 + wave) * 64 + lane) * 8;
        bf16x8 rh = *(const bf16x8*)(Wr1h + wi);
        bf16x8 rl = *(const bf16x8*)(Wr1l + wi);
        bf16x8 sh = *(const bf16x8*)(Ws1h + wi);
        bf16x8 sl = *(const bf16x8*)(Ws1l + wi);
#pragma unroll
        for (int nf = 0; nf < NF1; ++nf) {
            const int gc  = nf * 16 + l15;
            const int byo = gc * 256 + ((ks * 64 + lq * 16) ^ ((gc & 7) << 4));
            bf16x8 g = *(const bf16x8*)(lds + R_B + byo);
            r1[nf] = __builtin_amdgcn_mfma_f32_16x16x32_bf16(rh, g, r1[nf], 0, 0, 0);
            r1[nf] = __builtin_amdgcn_mfma_f32_16x16x32_bf16(rl, g, r1[nf], 0, 0, 0);
            s1[nf] = __builtin_amdgcn_mfma_f32_16x16x32_bf16(sh, g, s1[nf], 0, 0, 0);
            s1[nf] = __builtin_amdgcn_mfma_f32_16x16x32_bf16(sl, g, s1[nf], 0, 0, 0);
        }
    }
    __syncthreads();   // B3

    // epilogue1: y1 = r1 + br1 + x_exact; y1h -> R_B; y1l -> R_C (opt); skip1
    {
        const float4 br1v = *(const float4*)(br1 + ch0);
        const float4 bs1v = *(const float4*)(bs1 + ch0);
#pragma unroll
        for (int nf = 0; nf < NF1; ++nf) {
            const int yc = nf * 16 + l15;
            const int c  = t0 - H1 + yc;
            const int pcx = yc + O1;
            bf16x4 xh = *(const bf16x4*)(lds + pcx * 256 + ((ch0 * 2) ^ ((pcx & 7) << 4)));
            int cg = c < 0 ? 0 : (c > TFULL - 1 ? TFULL - 1 : c);
            bf16x4 xl = *(const bf16x4*)(curl + xbase + (size_t)cg * RC + ch0);
            bf16x4 yh4, yl4;
            float sk[4];
#pragma unroll
            for (int r = 0; r < 4; ++r) {
                float xe = bf2f((unsigned short)xh[r]) + bf2f((unsigned short)xl[r]);
                float y  = r1[nf][r] + ((const float*)&br1v)[r] + xe;
                unsigned short h = f2bf(y);
                yh4[r] = (short)h;
                yl4[r] = (short)f2bf(y - bf2f(h));
                sk[r]  = s1[nf][r] + ((const float*)&bs1v)[r];
            }
            *(bf16x4*)(lds + R_B + yc * 256 + ((ch0 * 2) ^ ((yc & 7) << 4))) = yh4;
            if constexpr (KEEPY1L) {
                if (nf >= FQ) {
                    const int lc2 = yc - (H1 - H2);
                    *(bf16x4*)(lds + R_C + lc2 * 256 + ((ch0 * 2) ^ ((lc2 & 7) << 4))) = yl4;
                }
            }
            if (nf >= FH1) {
                const int lc = yc - H1;
                if (lc < nt && c >= TFULL - SKIP_SZ) {
                    float* sp = skip1 + ((size_t)b * RC + ch0) * SKIP_SZ + (c - (TFULL - SKIP_SZ));
#pragma unroll
                    for (int r = 0; r < 4; ++r) sp[(size_t)r * SKIP_SZ] = sk[r];
                }
            }
        }
    }
    __syncthreads();   // B4 (y1h ready; X dead)

    // ======== sub-block 2 ========
    f32x4 a2[NF2];
#pragma unroll
    for (int nf = 0; nf < NF2; ++nf) a2[nf] = (f32x4){0.f, 0.f, 0.f, 0.f};
#pragma unroll
    for (int ks = 0; ks < 8; ++ks) {
        const int tap = ks >> 2;
        const int kk  = ks & 3;
        const size_t wi = ((size_t)(ks * 8 + wave) * 64 + lane) * 8;
        bf16x8 ah = *(const bf16x8*)(Wd2h + wi);
        bf16x8 al = *(const bf16x8*)(Wd2l + wi);
#pragma unroll
        for (int nf = 0; nf < NF2; ++nf) {
            const int pc  = nf * 16 + l15 + (tap ? Q1 : Q0);
            const int byo = pc * 256 + ((kk * 64 + lq * 16) ^ ((pc & 7) << 4));
            bf16x8 bh = *(const bf16x8*)(lds + R_B + byo);
            a2[nf] = __builtin_amdgcn_mfma_f32_16x16x32_bf16(ah, bh, a2[nf], 0, 0, 0);
            a2[nf] = __builtin_amdgcn_mfma_f32_16x16x32_bf16(al, bh, a2[nf], 0, 0, 0);
        }
    }
    // gate2 -> R_X (X dead after B4)
#pragma unroll
    for (int nf = 0; nf < NF2; ++nf) {
        const int gc  = nf * 16 + l15;
        const int byo = gc * 256 + ((ch0 * 2) ^ ((gc & 7) << 4));
        bf16x4 hv;
#pragma unroll
        for (int r = 0; r < 4; ++r)
            hv[r] = (short)f2bf(gatef(a2[nf][r]));
        *(bf16x4*)(lds + byo) = hv;
    }
    __syncthreads();   // B5

    f32x4 r2[NF2], s2[NF2];
#pragma unroll
    for (int nf = 0; nf < NF2; ++nf) {
        r2[nf] = (f32x4){0.f, 0.f, 0.f, 0.f};
        s2[nf] = (f32x4){0.f, 0.f, 0.f, 0.f};
    }
#pragma unroll
    for (int ks = 0; ks < 4; ++ks) {
        const size_t wi = ((size_t)(ks * 8 + wave) * 64 + lane) * 8;
        bf16x8 rh = *(const bf16x8*)(Wr2h + wi);
        bf16x8 rl = *(const bf16x8*)(Wr2l + wi);
        bf16x8 sh = *(const bf16x8*)(Ws2h + wi);
        bf16x8 sl = *(const bf16x8*)(Ws2l + wi);
#pragma unroll
        for (int nf = 0; nf < NF2; ++nf) {
            const int gc  = nf * 16 + l15;
            const int byo = gc * 256 + ((ks * 64 + lq * 16) ^ ((gc & 7) << 4));
            bf16x8 g = *(const bf16x8*)(lds + byo);
            r2[nf] = __builtin_amdgcn_mfma_f32_16x16x32_bf16(rh, g, r2[nf], 0, 0, 0);
            r2[nf] = __builtin_amdgcn_mfma_f32_16x16x32_bf16(rl, g, r2[nf], 0, 0, 0);
            s2[nf] = __builtin_amdgcn_mfma_f32_16x16x32_bf16(sh, g, s2[nf], 0, 0, 0);
            s2[nf] = __builtin_amdgcn_mfma_f32_16x16x32_bf16(sl, g, s2[nf], 0, 0, 0);
        }
    }
    __syncthreads();   // B6

    // epilogue2: y2 = r2 + br2 + y1; y2h -> R_X (g2 dead); skip2
    {
        const float4 br2v = *(const float4*)(br2 + ch0);
        const float4 bs2v = *(const float4*)(bs2 + ch0);
#pragma unroll
        for (int nf = 0; nf < NF2; ++nf) {
            const int yc = nf * 16 + l15;
            const int c  = t0 - H2 + yc;
            const int y1c = yc + Q1;
            bf16x4 yh = *(const bf16x4*)(lds + R_B + y1c * 256 + ((ch0 * 2) ^ ((y1c & 7) << 4)));
            bf16x4 yl;
            if constexpr (KEEPY1L)
                yl = *(const bf16x4*)(lds + R_C + yc * 256 + ((ch0 * 2) ^ ((yc & 7) << 4)));
            bf16x4 y2h4;
            float sk[4];
#pragma unroll
            for (int r = 0; r < 4; ++r) {
                float y1e = bf2f((unsigned short)yh[r]);
                if constexpr (KEEPY1L) y1e += bf2f((unsigned short)yl[r]);
                float y = r2[nf][r] + ((const float*)&br2v)[r] + y1e;
                y2h4[r] = (short)f2bf(y);      // y2 lo dropped (1 rounding)
                sk[r] = s2[nf][r] + ((const float*)&bs2v)[r];
            }
            *(bf16x4*)(lds + yc * 256 + ((ch0 * 2) ^ ((yc & 7) << 4))) = y2h4;
            if (nf >= FH2) {
                const int lc = yc - H2;
                if (lc < nt && c >= TFULL - SKIP_SZ) {
                    float* sp = skip2 + ((size_t)b * RC + ch0) * SKIP_SZ + (c - (TFULL - SKIP_SZ));
#pragma unroll
                    for (int r = 0; r < 4; ++r) sp[(size_t)r * SKIP_SZ] = sk[r];
                }
            }
        }
    }
    __syncthreads();   // B7 (y2h ready; y1h dead)

    // ======== sub-block 3 (core) ========
    f32x4 a3[4];
#pragma unroll
    for (int nf = 0; nf < 4; ++nf) a3[nf] = (f32x4){0.f, 0.f, 0.f, 0.f};
#pragma unroll
    for (int ks = 0; ks < 8; ++ks) {
        const int tap = ks >> 2;
        const int kk  = ks & 3;
        const size_t wi = ((size_t)(ks * 8 + wave) * 64 + lane) * 8;
        bf16x8 ah = *(const bf16x8*)(Wd3h + wi);
        bf16x8 al = *(const bf16x8*)(Wd3l + wi);
#pragma unroll
        for (int nf = 0; nf < 4; ++nf) {
            const int pc  = nf * 16 + l15 + (tap ? P1 : P0);
            const int byo = pc * 256 + ((kk * 64 + lq * 16) ^ ((pc & 7) << 4));
            bf16x8 bh = *(const bf16x8*)(lds + byo);
            a3[nf] = __builtin_amdgcn_mfma_f32_16x16x32_bf16(ah, bh, a3[nf], 0, 0, 0);
            a3[nf] = __builtin_amdgcn_mfma_f32_16x16x32_bf16(al, bh, a3[nf], 0, 0, 0);
        }
    }
    // gate3 -> R_B (y1h dead after B7)
#pragma unroll
    for (int nf = 0; nf < 4; ++nf) {
        const int gc  = nf * 16 + l15;
        const int byo = gc * 256 + ((ch0 * 2) ^ ((gc & 7) << 4));
        bf16x4 hv;
#pragma unroll
        for (int r = 0; r < 4; ++r)
            hv[r] = (short)f2bf(gatef(a3[nf][r]));
        *(bf16x4*)(lds + R_B + byo) = hv;
    }
    __syncthreads();   // B8

    f32x4 r3[4], s3[4];
#pragma unroll
    for (int nf = 0; nf < 4; ++nf) {
        r3[nf] = (f32x4){0.f, 0.f, 0.f, 0.f};
        s3[nf] = (f32x4){0.f, 0.f, 0.f, 0.f};
    }
#pragma unroll
    for (int ks = 0; ks < 4; ++ks) {
        const size_t wi = ((size_t)(ks * 8 + wave) * 64 + lane) * 8;
        bf16x8 rh = *(const bf16x8*)(Wr3h + wi);
        bf16x8 rl = *(const bf16x8*)(Wr3l + wi);
        bf16x8 sh = *(const bf16x8*)(Ws3h + wi);
        bf16x8 sl = *(const bf16x8*)(Ws3l + wi);
#pragma unroll
        for (int nf = 0; nf < 4; ++nf) {
            const int gc  = nf * 16 + l15;
            const int byo = gc * 256 + ((ks * 64 + lq * 16) ^ ((gc & 7) << 4));
            bf16x8 g = *(const bf16x8*)(lds + R_B + byo);
            r3[nf] = __builtin_amdgcn_mfma_f32_16x16x32_bf16(rh, g, r3[nf], 0, 0, 0);
            r3[nf] = __builtin_amdgcn_mfma_f32_16x16x32_bf16(rl, g, r3[nf], 0, 0, 0);
            s3[nf] = __builtin_amdgcn_mfma_f32_16x16x32_bf16(sh, g, s3[nf], 0, 0, 0);
            s3[nf] = __builtin_amdgcn_mfma_f32_16x16x32_bf16(sl, g, s3[nf], 0, 0, 0);
        }
    }

    // epilogue3: y3 = r3 + br3 + y2h (bf16); fresh hi/lo split -> global; skip3
    {
        const float4 br3v = *(const float4*)(br3 + ch0);
        const float4 bs3v = *(const float4*)(bs3 + ch0);
#pragma unroll
        for (int nf = 0; nf < 4; ++nf) {
            const int lc = nf * 16 + l15;
            if (lc < nt) {
                const int c  = t0 + lc;
                const int yc = lc + H2;
                bf16x4 yh = *(const bf16x4*)(lds + yc * 256 + ((ch0 * 2) ^ ((yc & 7) << 4)));
                bf16x4 oh, ol;
                float sk[4];
#pragma unroll
                for (int r = 0; r < 4; ++r) {
                    float y = r3[nf][r] + ((const float*)&br3v)[r] + bf2f((unsigned short)yh[r]);
                    unsigned short h = f2bf(y);
                    oh[r] = (short)h;
                    ol[r] = (short)f2bf(y - bf2f(h));
                    sk[r] = s3[nf][r] + ((const float*)&bs3v)[r];
                }
                const size_t off = xbase + (size_t)c * RC + ch0;
                *(bf16x4*)(nxth + off) = oh;
                *(bf16x4*)(nxtl + off) = ol;
                if (c >= TFULL - SKIP_SZ) {
                    float* sp = skip3 + ((size_t)b * RC + ch0) * SKIP_SZ + (c - (TFULL - SKIP_SZ));
#pragma unroll
                    for (int r = 0; r < 4; ++r) sp[(size_t)r * SKIP_SZ] = sk[r];
                }
            }
        }
    }
}

extern "C" void kernel_launch(void* const* d_in, const int* in_sizes, int n_in,
                              void* d_out, int out_size, void* d_ws, size_t ws_size,
                              hipStream_t stream) {
    const float* x  = (const float*)d_in[0];
    const float* Wd = (const float*)d_in[1];
    const float* Wr = (const float*)d_in[2];
    const float* br = (const float*)d_in[3];
    const float* Ws = (const float*)d_in[4];
    const float* bs = (const float*)d_in[5];
    float* out = (float*)d_out;

    const size_t SLOT = (size_t)BATCH * TFULL * RC;
    unsigned short* Xs0h = (unsigned short*)d_ws;
    unsigned short* Xs0l = Xs0h + SLOT;
    unsigned short* Xs1h = Xs0l + SLOT;
    unsigned short* Xs1l = Xs1h + SLOT;
    unsigned short* Wdh = Xs1l + SLOT;
    unsigned short* Wdl = Wdh + (size_t)NB * 32768;
    unsigned short* Wrh = Wdl + (size_t)NB * 32768;
    unsigned short* Wrl = Wrh + (size_t)NB * 16384;
    unsigned short* Wsh = Wrl + (size_t)NB * 16384;
    unsigned short* Wsl = Wsh + (size_t)NB * 16384;

    xpose_split<<<dim3(TFULL / 64, RC / 32, BATCH), 256, 0, stream>>>(x, Xs0h, Xs0l);
    {
        int total = NB * 4096 + 2 * NB * 2048;
        wpack<<<dim3((total + 255) / 256), 256, 0, stream>>>(Wd, Wr, Ws, Wdh, Wdl, Wrh, Wrl, Wsh, Wsl);
    }

    int L = TFULL;
    int pp = 0;
    for (int s = 0; s < 4; ++s) {
        // triple A: blocks s*10+0..2 (d = 1,2,4)
        {
            const int i = s * 10;
            const int Lout = L - 7;
            const int col0 = TFULL - Lout;
            const int units = ((Lout + 63) >> 6) * BATCH;
            unsigned short* curh = pp ? Xs1h : Xs0h;
            unsigned short* curl = pp ? Xs1l : Xs0l;
            unsigned short* nxth = pp ? Xs0h : Xs1h;
            unsigned short* nxtl = pp ? Xs0l : Xs1l;
            wn_triple<1, 2, 4, 48, 32, 16, true><<<dim3(units), dim3(512), 0, stream>>>(
                curh, curl, nxth, nxtl, Wdh, Wdl, Wrh, Wrl, Wsh, Wsl,
                br, bs, out, i, col0);
            pp ^= 1;
            L = Lout;
        }
        // triple B: blocks s*10+3..5 (d = 8,16,32)
        {
            const int i = s * 10 + 3;
            const int Lout = L - 56;
            const int col0 = TFULL - Lout;
            const int units = ((Lout + 63) >> 6) * BATCH;
            unsigned short* curh = pp ? Xs1h : Xs0h;
            unsigned short* curl = pp ? Xs1l : Xs0l;
            unsigned short* nxth = pp ? Xs0h : Xs1h;
            unsigned short* nxtl = pp ? Xs0l : Xs1l;
            wn_triple<8, 16, 32, 56, 48, 32, false><<<dim3(units), dim3(512), 0, stream>>>(
                curh, curl, nxth, nxtl, Wdh, Wdl, Wrh, Wrl, Wsh, Wsl,
                br, bs, out, i, col0);
            pp ^= 1;
            L = Lout;
        }
        // singles: d = 64, 128, 256, 512
        for (int q = 6; q < 10; ++q) {
            const int i = s * 10 + q;
            const int d = 1 << q;
            const int Lout = L - d;
            const int col0 = TFULL - Lout;
            const int units = ((Lout + 63) >> 6) * BATCH;
            unsigned short* curh = pp ? Xs1h : Xs0h;
            unsigned short* curl = pp ? Xs1l : Xs0l;
            unsigned short* nxth = pp ? Xs0h : Xs1h;
            unsigned short* nxtl = pp ? Xs0l : Xs1l;
            wn_step<<<dim3(units), dim3(512), 0, stream>>>(
                curh, curl, nxth, nxtl,
                Wdh + (size_t)i * 32768, Wdl + (size_t)i * 32768,
                Wrh + (size_t)i * 16384, Wrl + (size_t)i * 16384,
                Wsh + (size_t)i * 16384, Wsl + (size_t)i * 16384,
                br + (size_t)i * RC, bs + (size_t)i * RC,
                out + (size_t)i * BATCH * RC * SKIP_SZ, d, col0);
            pp ^= 1;
            L = Lout;
        }
    }
}

// Round 15
// 617.292 us; speedup vs baseline: 1.3076x; 1.0513x over previous
//
#include <hip/hip_runtime.h>

typedef __attribute__((ext_vector_type(8))) short bf16x8;
typedef __attribute__((ext_vector_type(4))) short bf16x4;
typedef __attribute__((ext_vector_type(4))) float f32x4;

#define TFULL 8192
#define RC 128
#define NB 40
#define BATCH 4
#define SKIP_SZ 4096

#define LDS3(p) ((__attribute__((address_space(3))) void*)(p))
#define GLB1(p) ((const __attribute__((address_space(1))) void*)(p))

// ---- single-block kernel LDS (R12/R14 proven layout) ----
#define XPLANE 16384
#define LDS_BYTES (3 * XPLANE)   // 48 KB

__device__ __forceinline__ unsigned short f2bf(float f) {
    unsigned u = __builtin_bit_cast(unsigned, f);
    u += 0x7FFFu + ((u >> 16) & 1u);          // round-to-nearest-even
    return (unsigned short)(u >> 16);
}
__device__ __forceinline__ float bf2f(unsigned short h) {
    unsigned u = ((unsigned)h) << 16;
    return __builtin_bit_cast(float, u);
}
// tanh(y)*sigmoid(y) via one fast exp (clamped; saturation exact).
__device__ __forceinline__ float gatef(float y) {
    float yc = fminf(fmaxf(y, -30.f), 30.f);
    float e  = __expf(-yc);
    float e2 = e * e;
    return (1.f - e2) * __builtin_amdgcn_rcpf(1.f + e2)
                      * __builtin_amdgcn_rcpf(1.f + e);
}

// ---------------------------------------------------------------------------
// Merged pre-pass: blocks [0,2048) transpose+split x; blocks [2048,3328)
// pack weights into per-MFMA-A-fragment layout (hi/lo bf16).
// ---------------------------------------------------------------------------
__global__ __launch_bounds__(256) void prepass(
    const float* __restrict__ x,
    const float* __restrict__ Wd, const float* __restrict__ Wr, const float* __restrict__ Ws,
    unsigned short* __restrict__ Xh, unsigned short* __restrict__ Xl,
    unsigned short* __restrict__ Wdh, unsigned short* __restrict__ Wdl,
    unsigned short* __restrict__ Wrh, unsigned short* __restrict__ Wrl,
    unsigned short* __restrict__ Wsh, unsigned short* __restrict__ Wsl)
{
    __shared__ float t[32][65];
    const int bx  = blockIdx.x;
    const int tid = threadIdx.x;
    if (bx < 2048) {
        // transpose x [B][128ch][8192col] fp32 -> hi/lo bf16 [B][col][ch]
        const int col0 = (bx & 127) * 64;
        const int ch0  = ((bx >> 7) & 3) * 32;
        const int b    = bx >> 9;
        const int tx = tid & 63, ty = tid >> 6;
#pragma unroll
        for (int i = 0; i < 8; ++i) {
            int ch = ty + i * 4;
            t[ch][tx] = x[((size_t)(b * RC + ch0 + ch)) * TFULL + col0 + tx];
        }
        __syncthreads();
        for (int idx = tid; idx < 64 * 32; idx += 256) {
            int col = idx >> 5, ch = idx & 31;
            float v = t[ch][col];
            unsigned short h = f2bf(v);
            unsigned short l = f2bf(v - bf2f(h));
            size_t off = ((size_t)(b * TFULL + col0 + col)) * RC + ch0 + ch;
            Xh[off] = h;
            Xl[off] = l;
        }
        return;
    }
    // weight pack. A[m][k]: lane l holds m=16*mf+(l&15), k=32*ks+(l>>4)*8+j.
    const int Nd = NB * 4096;
    const int Nr = NB * 2048;
    int id = (bx - 2048) * 256 + tid;
    const float* src;
    unsigned short *dh, *dl;
    int blk, rloc;
    bool dil = false;
    size_t dbase;
    if (id < Nd)               { dil = true; blk = id >> 12; rloc = id & 4095; dh = Wdh; dl = Wdl; src = Wd; dbase = (size_t)id * 8; }
    else if (id < Nd + Nr)     { int u = id - Nd;      blk = u >> 11; rloc = u & 2047; dh = Wrh; dl = Wrl; src = Wr; dbase = (size_t)u * 8; }
    else if (id < Nd + 2 * Nr) { int u = id - Nd - Nr; blk = u >> 11; rloc = u & 2047; dh = Wsh; dl = Wsl; src = Ws; dbase = (size_t)u * 8; }
    else return;
    const int ks = rloc >> 9, mf = (rloc >> 6) & 7, lane = rloc & 63;
    const int m = mf * 16 + (lane & 15);
    const int kb = ks * 32 + ((lane >> 4) << 3);
    bf16x8 hv, lv;
#pragma unroll
    for (int j = 0; j < 8; ++j) {
        int k = kb + j;
        float w;
        if (dil) {
            int tap = k >> 7, i = k & 127;
            w = src[((((size_t)blk * 128 + m) * 128) + i) * 2 + tap];
        } else {
            w = src[(((size_t)blk * 128 + m) * 128) + k];
        }
        unsigned short h = f2bf(w);
        hv[j] = (short)h;
        lv[j] = (short)f2bf(w - bf2f(h));
    }
    *(bf16x8*)(dh + dbase) = hv;
    *(bf16x8*)(dl + dbase) = lv;
}

// ---------------------------------------------------------------------------
// Single-block step (R12/R14 proven; skip GEMM now single-product).
// ---------------------------------------------------------------------------
__global__ __launch_bounds__(512, 4) void wn_step(
    const unsigned short* __restrict__ curh, const unsigned short* __restrict__ curl,
    unsigned short* __restrict__ nxth, unsigned short* __restrict__ nxtl,
    const unsigned short* __restrict__ Wdh_i, const unsigned short* __restrict__ Wdl_i,
    const unsigned short* __restrict__ Wrh_i, const unsigned short* __restrict__ Wrl_i,
    const unsigned short* __restrict__ Wsh_i,
    const float* __restrict__ br, const float* __restrict__ bs,
    float* __restrict__ skip, int d, int col0)
{
    __shared__ char lds[LDS_BYTES];

    const int tid  = threadIdx.x;
    const int lane = tid & 63;
    const int wave = tid >> 6;
    const int l15  = lane & 15, lq = lane >> 4;
    const int u    = blockIdx.x;
    const int b    = u & 3;
    const int tile0 = col0 + (u >> 2) * 64;
    const size_t xbase = (size_t)b * TFULL * RC;

#pragma unroll
    for (int r = 0; r < 4; ++r) {
        const int j   = wave * 4 + r;
        const int tap = j >> 4;
        const int c4  = (j & 15) * 4;
        const int col = c4 + lq;
        const int chs = l15 ^ (col & 7);
        int cg_ = tile0 + col;
        cg_ = cg_ > TFULL - 1 ? TFULL - 1 : cg_;
        if (!tap) cg_ -= d;
        const unsigned short* gsrc = curh + xbase + (size_t)cg_ * RC + chs * 8;
        char* ldst = lds + tap * XPLANE + c4 * 256;
        __builtin_amdgcn_global_load_lds(GLB1(gsrc), LDS3(ldst), 16, 0, 0);
    }
    __syncthreads();

    f32x4 acc[4];
#pragma unroll
    for (int nf = 0; nf < 4; ++nf) acc[nf] = (f32x4){0.f, 0.f, 0.f, 0.f};

#pragma unroll
    for (int ks = 0; ks < 8; ++ks) {
        const int tap = ks >> 2;
        const int kk  = ks & 3;
        const size_t wi = ((size_t)(ks * 8 + wave) * 64 + lane) * 8;
        bf16x8 ah = *(const bf16x8*)(Wdh_i + wi);
        bf16x8 al = *(const bf16x8*)(Wdl_i + wi);
#pragma unroll
        for (int nf = 0; nf < 4; ++nf) {
            const int col = nf * 16 + l15;
            const int byo = (kk * 64 + lq * 16) ^ ((col & 7) << 4);
            bf16x8 bh = *(const bf16x8*)(lds + tap * XPLANE + col * 256 + byo);
            acc[nf] = __builtin_amdgcn_mfma_f32_16x16x32_bf16(ah, bh, acc[nf], 0, 0, 0);
            acc[nf] = __builtin_amdgcn_mfma_f32_16x16x32_bf16(al, bh, acc[nf], 0, 0, 0);
        }
    }

    const int ch0 = wave * 16 + lq * 4;
#pragma unroll
    for (int nf = 0; nf < 4; ++nf) {
        const int n   = nf * 16 + l15;
        const int byo = (ch0 * 2) ^ ((n & 7) << 4);
        bf16x4 hv;
#pragma unroll
        for (int r = 0; r < 4; ++r)
            hv[r] = (short)f2bf(gatef(acc[nf][r]));
        *(bf16x4*)(lds + 2 * XPLANE + n * 256 + byo) = hv;
    }
    __syncthreads();

    f32x4 accr[4], accs[4];
#pragma unroll
    for (int nf = 0; nf < 4; ++nf) {
        accr[nf] = (f32x4){0.f, 0.f, 0.f, 0.f};
        accs[nf] = (f32x4){0.f, 0.f, 0.f, 0.f};
    }
#pragma unroll
    for (int ks = 0; ks < 4; ++ks) {
        const size_t wi = ((size_t)(ks * 8 + wave) * 64 + lane) * 8;
        bf16x8 rh = *(const bf16x8*)(Wrh_i + wi);
        bf16x8 rl = *(const bf16x8*)(Wrl_i + wi);
        bf16x8 sh = *(const bf16x8*)(Wsh_i + wi);
#pragma unroll
        for (int nf = 0; nf < 4; ++nf) {
            const int col = nf * 16 + l15;
            const int byo = (ks * 64 + lq * 16) ^ ((col & 7) << 4);
            bf16x8 g = *(const bf16x8*)(lds + 2 * XPLANE + col * 256 + byo);
            accr[nf] = __builtin_amdgcn_mfma_f32_16x16x32_bf16(rh, g, accr[nf], 0, 0, 0);
            accr[nf] = __builtin_amdgcn_mfma_f32_16x16x32_bf16(rl, g, accr[nf], 0, 0, 0);
            accs[nf] = __builtin_amdgcn_mfma_f32_16x16x32_bf16(sh, g, accs[nf], 0, 0, 0);
        }
    }

    const int nt = TFULL - tile0 < 64 ? TFULL - tile0 : 64;
    const float4 brv = *(const float4*)(br + ch0);
    const float4 bsv = *(const float4*)(bs + ch0);
#pragma unroll
    for (int nf = 0; nf < 4; ++nf) {
        const int n = nf * 16 + l15;
        if (n < nt) {
            const int c = tile0 + n;
            const int byo = (ch0 * 2) ^ ((n & 7) << 4);
            bf16x4 ih = *(const bf16x4*)(lds + XPLANE + n * 256 + byo);
            const size_t off = xbase + (size_t)c * RC + ch0;
            bf16x4 il = *(const bf16x4*)(curl + off);
            bf16x4 oh, ol;
            float sk[4];
#pragma unroll
            for (int r = 0; r < 4; ++r) {
                float inv = bf2f((unsigned short)ih[r]) + bf2f((unsigned short)il[r]);
                float rv = accr[nf][r] + ((const float*)&brv)[r] + inv;
                unsigned short h = f2bf(rv);
                oh[r] = (short)h;
                ol[r] = (short)f2bf(rv - bf2f(h));
                sk[r] = accs[nf][r] + ((const float*)&bsv)[r];
            }
            *(bf16x4*)(nxth + off) = oh;
            *(bf16x4*)(nxtl + off) = ol;
            if (c >= TFULL - SKIP_SZ) {
                float* sp = skip + ((size_t)b * RC + ch0) * SKIP_SZ + (c - (TFULL - SKIP_SZ));
#pragma unroll
                for (int r = 0; r < 4; ++r) sp[(size_t)r * SKIP_SZ] = sk[r];
            }
        }
    }
}

// ---------------------------------------------------------------------------
// Stage X-hi into RX region: cols [0,RXC) = global [t0-STGHB, t0+64),
// pre-swizzled global source chunk, linear LDS dest.
// ---------------------------------------------------------------------------
template<int RXC, int STGHB>
__device__ __forceinline__ void stage_x(char* lds, const unsigned short* __restrict__ curh,
                                        size_t xbase, int t0)
{
    const int tid  = threadIdx.x;
    const int lane = tid & 63;
    const int wave = tid >> 6;
    const int l15  = lane & 15, lq = lane >> 4;
#pragma unroll
    for (int j = wave; j < RXC / 4; j += 8) {
        const int c4  = j * 4;
        const int col = c4 + lq;
        const int chs = l15 ^ (col & 7);
        int g = t0 - STGHB + col;
        g = g < 0 ? 0 : (g > TFULL - 1 ? TFULL - 1 : g);
        const unsigned short* gsrc = curh + xbase + (size_t)g * RC + chs * 8;
        __builtin_amdgcn_global_load_lds(GLB1(gsrc), LDS3(lds + c4 * 256), 16, 0, 0);
    }
}

// ---------------------------------------------------------------------------
// One fused sub-block: conv (reads prev-y/X in src region) -> gate (dst) ->
// res/skip -> epilogue (y_h -> dst over gate; LAST: fresh hi/lo split to
// global). Template'd so regions/offsets/frag counts are compile-time
// (R11 lesson: runtime params spill). Skip GEMM single-product.
// Q1v = prev-window-start offset (tap1); Q0v = Q1v - D. HI = this block's
// halo (0 for LAST). FIRST adds exact-x lo from global.
// ---------------------------------------------------------------------------
template<int NF, int Q0v, int Q1v, int HI, bool FIRST, bool LAST>
__device__ __forceinline__ void wn_sub(
    char* lds, const int srcOff, const int dstOff,
    const unsigned short* __restrict__ Wdh_i, const unsigned short* __restrict__ Wdl_i,
    const unsigned short* __restrict__ Wrh_i, const unsigned short* __restrict__ Wrl_i,
    const unsigned short* __restrict__ Wsh_i,
    const float* __restrict__ br, const float* __restrict__ bs,
    const unsigned short* __restrict__ curl,
    unsigned short* __restrict__ nxth, unsigned short* __restrict__ nxtl,
    float* __restrict__ skip, int t0, int b, int nt)
{
    constexpr int FH = HI >> 4;
    const int tid  = threadIdx.x;
    const int lane = tid & 63;
    const int wave = tid >> 6;
    const int l15  = lane & 15, lq = lane >> 4;
    const int ch0  = wave * 16 + lq * 4;
    const size_t xbase = (size_t)b * TFULL * RC;

    // ---- dilated conv (2-product: Wh,Wl x prev-hi)
    f32x4 a[NF];
#pragma unroll
    for (int nf = 0; nf < NF; ++nf) a[nf] = (f32x4){0.f, 0.f, 0.f, 0.f};
#pragma unroll
    for (int ks = 0; ks < 8; ++ks) {
        const int tap = ks >> 2;
        const int kk  = ks & 3;
        const size_t wi = ((size_t)(ks * 8 + wave) * 64 + lane) * 8;
        bf16x8 ah = *(const bf16x8*)(Wdh_i + wi);
        bf16x8 al = *(const bf16x8*)(Wdl_i + wi);
#pragma unroll
        for (int nf = 0; nf < NF; ++nf) {
            const int pc  = nf * 16 + l15 + (tap ? Q1v : Q0v);
            const int byo = pc * 256 + ((kk * 64 + lq * 16) ^ ((pc & 7) << 4));
            bf16x8 bh = *(const bf16x8*)(lds + srcOff + byo);
            a[nf] = __builtin_amdgcn_mfma_f32_16x16x32_bf16(ah, bh, a[nf], 0, 0, 0);
            a[nf] = __builtin_amdgcn_mfma_f32_16x16x32_bf16(al, bh, a[nf], 0, 0, 0);
        }
    }

    // ---- gate -> dst
#pragma unroll
    for (int nf = 0; nf < NF; ++nf) {
        const int gc  = nf * 16 + l15;
        const int byo = gc * 256 + ((ch0 * 2) ^ ((gc & 7) << 4));
        bf16x4 hv;
#pragma unroll
        for (int r = 0; r < 4; ++r)
            hv[r] = (short)f2bf(gatef(a[nf][r]));
        *(bf16x4*)(lds + dstOff + byo) = hv;
    }
    __syncthreads();

    // ---- res (2-product) & skip (1-product)
    f32x4 rr[NF], ss[NF];
#pragma unroll
    for (int nf = 0; nf < NF; ++nf) {
        rr[nf] = (f32x4){0.f, 0.f, 0.f, 0.f};
        ss[nf] = (f32x4){0.f, 0.f, 0.f, 0.f};
    }
#pragma unroll
    for (int ks = 0; ks < 4; ++ks) {
        const size_t wi = ((size_t)(ks * 8 + wave) * 64 + lane) * 8;
        bf16x8 rh = *(const bf16x8*)(Wrh_i + wi);
        bf16x8 rl = *(const bf16x8*)(Wrl_i + wi);
        bf16x8 sh = *(const bf16x8*)(Wsh_i + wi);
#pragma unroll
        for (int nf = 0; nf < NF; ++nf) {
            const int gc  = nf * 16 + l15;
            const int byo = gc * 256 + ((ks * 64 + lq * 16) ^ ((gc & 7) << 4));
            bf16x8 g = *(const bf16x8*)(lds + dstOff + byo);
            rr[nf] = __builtin_amdgcn_mfma_f32_16x16x32_bf16(rh, g, rr[nf], 0, 0, 0);
            rr[nf] = __builtin_amdgcn_mfma_f32_16x16x32_bf16(rl, g, rr[nf], 0, 0, 0);
            ss[nf] = __builtin_amdgcn_mfma_f32_16x16x32_bf16(sh, g, ss[nf], 0, 0, 0);
        }
    }
    __syncthreads();

    // ---- epilogue
    const float4 brv = *(const float4*)(br + ch0);
    const float4 bsv = *(const float4*)(bs + ch0);
#pragma unroll
    for (int nf = 0; nf < NF; ++nf) {
        const int yc = nf * 16 + l15;
        const int c  = t0 - HI + yc;
        const int pc = yc + Q1v;
        bf16x4 ph = *(const bf16x4*)(lds + srcOff + pc * 256 + ((ch0 * 2) ^ ((pc & 7) << 4)));
        float resid[4];
#pragma unroll
        for (int r = 0; r < 4; ++r) resid[r] = bf2f((unsigned short)ph[r]);
        if constexpr (FIRST) {
            int cg = c < 0 ? 0 : (c > TFULL - 1 ? TFULL - 1 : c);
            bf16x4 xl = *(const bf16x4*)(curl + xbase + (size_t)cg * RC + ch0);
#pragma unroll
            for (int r = 0; r < 4; ++r) resid[r] += bf2f((unsigned short)xl[r]);
        }
        float yv[4], sk[4];
#pragma unroll
        for (int r = 0; r < 4; ++r) {
            yv[r] = rr[nf][r] + ((const float*)&brv)[r] + resid[r];
            sk[r] = ss[nf][r] + ((const float*)&bsv)[r];
        }
        if constexpr (LAST) {
            const int lc = yc;
            if (lc < nt) {
                bf16x4 oh, ol;
#pragma unroll
                for (int r = 0; r < 4; ++r) {
                    unsigned short h = f2bf(yv[r]);
                    oh[r] = (short)h;
                    ol[r] = (short)f2bf(yv[r] - bf2f(h));
                }
                const size_t off = xbase + (size_t)c * RC + ch0;
                *(bf16x4*)(nxth + off) = oh;
                *(bf16x4*)(nxtl + off) = ol;
                if (c >= TFULL - SKIP_SZ) {
                    float* sp = skip + ((size_t)b * RC + ch0) * SKIP_SZ + (c - (TFULL - SKIP_SZ));
#pragma unroll
                    for (int r = 0; r < 4; ++r) sp[(size_t)r * SKIP_SZ] = sk[r];
                }
            }
        } else {
            bf16x4 yh4;
#pragma unroll
            for (int r = 0; r < 4; ++r)
                yh4[r] = (short)f2bf(yv[r]);   // intermediate y lo dropped
            *(bf16x4*)(lds + dstOff + yc * 256 + ((ch0 * 2) ^ ((yc & 7) << 4))) = yh4;
            if (nf >= FH) {
                const int lc = yc - HI;
                if (lc < nt && c >= TFULL - SKIP_SZ) {
                    float* sp = skip + ((size_t)b * RC + ch0) * SKIP_SZ + (c - (TFULL - SKIP_SZ));
#pragma unroll
                    for (int r = 0; r < 4; ++r) sp[(size_t)r * SKIP_SZ] = sk[r];
                }
            }
        }
    }
}

// ---------------------------------------------------------------------------
// Fused QUINT (d = 1,2,4,8,16). H = 64,48,32,16,0; STGHB = 68.
// Regions ping-pong: RX: X -> g2/y2h -> g4/y4h | RB: g1/y1h -> g3/y3h -> g5.
// ---------------------------------------------------------------------------
__global__ __launch_bounds__(512, 4) void wn_quint(
    const unsigned short* __restrict__ curh, const unsigned short* __restrict__ curl,
    unsigned short* __restrict__ nxth, unsigned short* __restrict__ nxtl,
    const unsigned short* __restrict__ Wdh, const unsigned short* __restrict__ Wdl,
    const unsigned short* __restrict__ Wrh, const unsigned short* __restrict__ Wrl,
    const unsigned short* __restrict__ Wsh,
    const float* __restrict__ br_all, const float* __restrict__ bs_all,
    float* __restrict__ out, int blk, int col0)
{
    constexpr int STGHB = 68, RXC = 132;
    constexpr int RB = RXC * 256;            // 33792
    __shared__ char lds[RB + 8 * 16 * 256];  // 66560 B -> 2 WG/CU

    const int u  = blockIdx.x;
    const int b  = u & 3;
    const int t0 = col0 + (u >> 2) * 64;
    const size_t xbase = (size_t)b * TFULL * RC;
    const int nt = TFULL - t0 < 64 ? TFULL - t0 : 64;
    const size_t SKB = (size_t)BATCH * RC * SKIP_SZ;

    stage_x<RXC, STGHB>(lds, curh, xbase, t0);
    __syncthreads();

#define WQ(j) Wdh + (size_t)(blk+j)*32768, Wdl + (size_t)(blk+j)*32768, \
              Wrh + (size_t)(blk+j)*16384, Wrl + (size_t)(blk+j)*16384, \
              Wsh + (size_t)(blk+j)*16384, \
              br_all + (size_t)(blk+j)*RC, bs_all + (size_t)(blk+j)*RC, \
              curl, nxth, nxtl, out + (size_t)(blk+j)*SKB, t0, b, nt

    wn_sub<8,  3,  4, 64, true,  false>(lds, 0,  RB, WQ(0));
    __syncthreads();
    wn_sub<7, 14, 16, 48, false, false>(lds, RB, 0,  WQ(1));
    __syncthreads();
    wn_sub<6, 12, 16, 32, false, false>(lds, 0,  RB, WQ(2));
    __syncthreads();
    wn_sub<5,  8, 16, 16, false, false>(lds, RB, 0,  WQ(3));
    __syncthreads();
    wn_sub<4,  0, 16,  0, false, true >(lds, 0,  RB, WQ(4));
#undef WQ
}

// ---------------------------------------------------------------------------
// Fused PAIR (d = 32,64). H = 64,0; STGHB = 96.
// ---------------------------------------------------------------------------
__global__ __launch_bounds__(512, 4) void wn_pair2(
    const unsigned short* __restrict__ curh, const unsigned short* __restrict__ curl,
    unsigned short* __restrict__ nxth, unsigned short* __restrict__ nxtl,
    const unsigned short* __restrict__ Wdh, const unsigned short* __restrict__ Wdl,
    const unsigned short* __restrict__ Wrh, const unsigned short* __restrict__ Wrl,
    const unsigned short* __restrict__ Wsh,
    const float* __restrict__ br_all, const float* __restrict__ bs_all,
    float* __restrict__ out, int blk, int col0)
{
    constexpr int STGHB = 96, RXC = 160;
    constexpr int RB = RXC * 256;            // 40960
    __shared__ char lds[RB + 8 * 16 * 256];  // 73728 B -> 2 WG/CU

    const int u  = blockIdx.x;
    const int b  = u & 3;
    const int t0 = col0 + (u >> 2) * 64;
    const size_t xbase = (size_t)b * TFULL * RC;
    const int nt = TFULL - t0 < 64 ? TFULL - t0 : 64;
    const size_t SKB = (size_t)BATCH * RC * SKIP_SZ;

    stage_x<RXC, STGHB>(lds, curh, xbase, t0);
    __syncthreads();

#define WQ(j) Wdh + (size_t)(blk+j)*32768, Wdl + (size_t)(blk+j)*32768, \
              Wrh + (size_t)(blk+j)*16384, Wrl + (size_t)(blk+j)*16384, \
              Wsh + (size_t)(blk+j)*16384, \
              br_all + (size_t)(blk+j)*RC, bs_all + (size_t)(blk+j)*RC, \
              curl, nxth, nxtl, out + (size_t)(blk+j)*SKB, t0, b, nt

    wn_sub<8, 0, 32, 64, true,  false>(lds, 0,  RB, WQ(0));
    __syncthreads();
    wn_sub<4, 0, 64,  0, false, true >(lds, RB, 0,  WQ(1));
#undef WQ
}

extern "C" void kernel_launch(void* const* d_in, const int* in_sizes, int n_in,
                              void* d_out, int out_size, void* d_ws, size_t ws_size,
                              hipStream_t stream) {
    const float* x  = (const float*)d_in[0];
    const float* Wd = (const float*)d_in[1];
    const float* Wr = (const float*)d_in[2];
    const float* br = (const float*)d_in[3];
    const float* Ws = (const float*)d_in[4];
    const float* bs = (const float*)d_in[5];
    float* out = (float*)d_out;

    const size_t SLOT = (size_t)BATCH * TFULL * RC;
    unsigned short* Xs0h = (unsigned short*)d_ws;
    unsigned short* Xs0l = Xs0h + SLOT;
    unsigned short* Xs1h = Xs0l + SLOT;
    unsigned short* Xs1l = Xs1h + SLOT;
    unsigned short* Wdh = Xs1l + SLOT;
    unsigned short* Wdl = Wdh + (size_t)NB * 32768;
    unsigned short* Wrh = Wdl + (size_t)NB * 32768;
    unsigned short* Wrl = Wrh + (size_t)NB * 16384;
    unsigned short* Wsh = Wrl + (size_t)NB * 16384;
    unsigned short* Wsl = Wsh + (size_t)NB * 16384;

    prepass<<<dim3(3328), dim3(256), 0, stream>>>(
        x, Wd, Wr, Ws, Xs0h, Xs0l, Wdh, Wdl, Wrh, Wrl, Wsh, Wsl);

    int L = TFULL;
    int pp = 0;
    for (int s = 0; s < 4; ++s) {
        // quint: blocks s*10 .. s*10+4 (d = 1,2,4,8,16)
        {
            const int i = s * 10;
            const int Lout = L - 31;
            const int col0 = TFULL - Lout;
            const int units = ((Lout + 63) >> 6) * BATCH;
            unsigned short* curh = pp ? Xs1h : Xs0h;
            unsigned short* curl = pp ? Xs1l : Xs0l;
            unsigned short* nxth = pp ? Xs0h : Xs1h;
            unsigned short* nxtl = pp ? Xs0l : Xs1l;
            wn_quint<<<dim3(units), dim3(512), 0, stream>>>(
                curh, curl, nxth, nxtl, Wdh, Wdl, Wrh, Wrl, Wsh,
                br, bs, out, i, col0);
            pp ^= 1;
            L = Lout;
        }
        // pair: blocks s*10+5, +6 (d = 32, 64)
        {
            const int i = s * 10 + 5;
            const int Lout = L - 96;
            const int col0 = TFULL - Lout;
            const int units = ((Lout + 63) >> 6) * BATCH;
            unsigned short* curh = pp ? Xs1h : Xs0h;
            unsigned short* curl = pp ? Xs1l : Xs0l;
            unsigned short* nxth = pp ? Xs0h : Xs1h;
            unsigned short* nxtl = pp ? Xs0l : Xs1l;
            wn_pair2<<<dim3(units), dim3(512), 0, stream>>>(
                curh, curl, nxth, nxtl, Wdh, Wdl, Wrh, Wrl, Wsh,
                br, bs, out, i, col0);
            pp ^= 1;
            L = Lout;
        }
        // singles: d = 128, 256, 512
        for (int q = 7; q < 10; ++q) {
            const int i = s * 10 + q;
            const int d = 1 << q;
            const int Lout = L - d;
            const int col0 = TFULL - Lout;
            const int units = ((Lout + 63) >> 6) * BATCH;
            unsigned short* curh = pp ? Xs1h : Xs0h;
            unsigned short* curl = pp ? Xs1l : Xs0l;
            unsigned short* nxth = pp ? Xs0h : Xs1h;
            unsigned short* nxtl = pp ? Xs0l : Xs1l;
            wn_step<<<dim3(units), dim3(512), 0, stream>>>(
                curh, curl, nxth, nxtl,
                Wdh + (size_t)i * 32768, Wdl + (size_t)i * 32768,
                Wrh + (size_t)i * 16384, Wrl + (size_t)i * 16384,
                Wsh + (size_t)i * 16384,
                br + (size_t)i * RC, bs + (size_t)i * RC,
                out + (size_t)i * BATCH * RC * SKIP_SZ, d, col0);
            pp ^= 1;
            L = Lout;
        }
    }
}

// Round 16
// 524.057 us; speedup vs baseline: 1.5403x; 1.1779x over previous
//
#include <hip/hip_runtime.h>

typedef __attribute__((ext_vector_type(8))) short bf16x8;
typedef __attribute__((ext_vector_type(4))) short bf16x4;
typedef __attribute__((ext_vector_type(4))) float f32x4;

#define TFULL 8192
#define RC 128
#define NB 40
#define BATCH 4
#define SKIP_SZ 4096

#define LDS3(p) ((__attribute__((address_space(3))) void*)(p))
#define GLB1(p) ((const __attribute__((address_space(1))) void*)(p))

// ---- single-block kernel LDS ----
#define XPLANE 16384
#define LDS_BYTES (3 * XPLANE)   // 48 KB

__device__ __forceinline__ unsigned short f2bf(float f) {
    unsigned u = __builtin_bit_cast(unsigned, f);
    u += 0x7FFFu + ((u >> 16) & 1u);          // round-to-nearest-even
    return (unsigned short)(u >> 16);
}
__device__ __forceinline__ float bf2f(unsigned short h) {
    unsigned u = ((unsigned)h) << 16;
    return __builtin_bit_cast(float, u);
}
// tanh(y)*sigmoid(y) via one fast exp (clamped; saturation exact).
__device__ __forceinline__ float gatef(float y) {
    float yc = fminf(fmaxf(y, -30.f), 30.f);
    float e  = __expf(-yc);
    float e2 = e * e;
    return (1.f - e2) * __builtin_amdgcn_rcpf(1.f + e2)
                      * __builtin_amdgcn_rcpf(1.f + e);
}

// ---------------------------------------------------------------------------
// Merged pre-pass: blocks [0,2048) transpose+split x (hi/lo, stream spine
// stays exact); blocks [2048,3328) pack weights hi-ONLY into A-fragment
// layout (1-product everywhere: weight-lo is 2^-9 relative, below the
// already-invisible 2^-8 conv-input quantization — R10 evidence).
// ---------------------------------------------------------------------------
__global__ __launch_bounds__(256) void prepass(
    const float* __restrict__ x,
    const float* __restrict__ Wd, const float* __restrict__ Wr, const float* __restrict__ Ws,
    unsigned short* __restrict__ Xh, unsigned short* __restrict__ Xl,
    unsigned short* __restrict__ Wdh,
    unsigned short* __restrict__ Wrh,
    unsigned short* __restrict__ Wsh)
{
    __shared__ float t[32][65];
    const int bx  = blockIdx.x;
    const int tid = threadIdx.x;
    if (bx < 2048) {
        const int col0 = (bx & 127) * 64;
        const int ch0  = ((bx >> 7) & 3) * 32;
        const int b    = bx >> 9;
        const int tx = tid & 63, ty = tid >> 6;
#pragma unroll
        for (int i = 0; i < 8; ++i) {
            int ch = ty + i * 4;
            t[ch][tx] = x[((size_t)(b * RC + ch0 + ch)) * TFULL + col0 + tx];
        }
        __syncthreads();
        for (int idx = tid; idx < 64 * 32; idx += 256) {
            int col = idx >> 5, ch = idx & 31;
            float v = t[ch][col];
            unsigned short h = f2bf(v);
            unsigned short l = f2bf(v - bf2f(h));
            size_t off = ((size_t)(b * TFULL + col0 + col)) * RC + ch0 + ch;
            Xh[off] = h;
            Xl[off] = l;
        }
        return;
    }
    // weight pack (hi only). A[m][k]: lane l holds m=16*mf+(l&15),
    // k=32*ks+(l>>4)*8+j. Dilated k = tap*128 + i.
    const int Nd = NB * 4096;
    const int Nr = NB * 2048;
    int id = (bx - 2048) * 256 + tid;
    const float* src;
    unsigned short* dh;
    int blk, rloc;
    bool dil = false;
    size_t dbase;
    if (id < Nd)               { dil = true; blk = id >> 12; rloc = id & 4095; dh = Wdh; src = Wd; dbase = (size_t)id * 8; }
    else if (id < Nd + Nr)     { int u = id - Nd;      blk = u >> 11; rloc = u & 2047; dh = Wrh; src = Wr; dbase = (size_t)u * 8; }
    else if (id < Nd + 2 * Nr) { int u = id - Nd - Nr; blk = u >> 11; rloc = u & 2047; dh = Wsh; src = Ws; dbase = (size_t)u * 8; }
    else return;
    const int ks = rloc >> 9, mf = (rloc >> 6) & 7, lane = rloc & 63;
    const int m = mf * 16 + (lane & 15);
    const int kb = ks * 32 + ((lane >> 4) << 3);
    bf16x8 hv;
#pragma unroll
    for (int j = 0; j < 8; ++j) {
        int k = kb + j;
        float w;
        if (dil) {
            int tap = k >> 7, i = k & 127;
            w = src[((((size_t)blk * 128 + m) * 128) + i) * 2 + tap];
        } else {
            w = src[(((size_t)blk * 128 + m) * 128) + k];
        }
        hv[j] = (short)f2bf(w);
    }
    *(bf16x8*)(dh + dbase) = hv;
}

// ---------------------------------------------------------------------------
// Single-block step: 512 thr, wave = mf slot x 64 cols; 1-product GEMMs,
// stream exact hi/lo via epilogue.
// ---------------------------------------------------------------------------
__global__ __launch_bounds__(512, 4) void wn_step(
    const unsigned short* __restrict__ curh, const unsigned short* __restrict__ curl,
    unsigned short* __restrict__ nxth, unsigned short* __restrict__ nxtl,
    const unsigned short* __restrict__ Wdh_i,
    const unsigned short* __restrict__ Wrh_i,
    const unsigned short* __restrict__ Wsh_i,
    const float* __restrict__ br, const float* __restrict__ bs,
    float* __restrict__ skip, int d, int col0)
{
    __shared__ char lds[LDS_BYTES];

    const int tid  = threadIdx.x;
    const int lane = tid & 63;
    const int wave = tid >> 6;
    const int l15  = lane & 15, lq = lane >> 4;
    const int u    = blockIdx.x;
    const int b    = u & 3;
    const int tile0 = col0 + (u >> 2) * 64;
    const size_t xbase = (size_t)b * TFULL * RC;

#pragma unroll
    for (int r = 0; r < 4; ++r) {
        const int j   = wave * 4 + r;
        const int tap = j >> 4;
        const int c4  = (j & 15) * 4;
        const int col = c4 + lq;
        const int chs = l15 ^ (col & 7);
        int cg_ = tile0 + col;
        cg_ = cg_ > TFULL - 1 ? TFULL - 1 : cg_;
        if (!tap) cg_ -= d;
        const unsigned short* gsrc = curh + xbase + (size_t)cg_ * RC + chs * 8;
        char* ldst = lds + tap * XPLANE + c4 * 256;
        __builtin_amdgcn_global_load_lds(GLB1(gsrc), LDS3(ldst), 16, 0, 0);
    }
    __syncthreads();

    f32x4 acc[4];
#pragma unroll
    for (int nf = 0; nf < 4; ++nf) acc[nf] = (f32x4){0.f, 0.f, 0.f, 0.f};

#pragma unroll
    for (int ks = 0; ks < 8; ++ks) {
        const int tap = ks >> 2;
        const int kk  = ks & 3;
        const size_t wi = ((size_t)(ks * 8 + wave) * 64 + lane) * 8;
        bf16x8 ah = *(const bf16x8*)(Wdh_i + wi);
#pragma unroll
        for (int nf = 0; nf < 4; ++nf) {
            const int col = nf * 16 + l15;
            const int byo = (kk * 64 + lq * 16) ^ ((col & 7) << 4);
            bf16x8 bh = *(const bf16x8*)(lds + tap * XPLANE + col * 256 + byo);
            acc[nf] = __builtin_amdgcn_mfma_f32_16x16x32_bf16(ah, bh, acc[nf], 0, 0, 0);
        }
    }

    const int ch0 = wave * 16 + lq * 4;
#pragma unroll
    for (int nf = 0; nf < 4; ++nf) {
        const int n   = nf * 16 + l15;
        const int byo = (ch0 * 2) ^ ((n & 7) << 4);
        bf16x4 hv;
#pragma unroll
        for (int r = 0; r < 4; ++r)
            hv[r] = (short)f2bf(gatef(acc[nf][r]));
        *(bf16x4*)(lds + 2 * XPLANE + n * 256 + byo) = hv;
    }
    __syncthreads();

    f32x4 accr[4], accs[4];
#pragma unroll
    for (int nf = 0; nf < 4; ++nf) {
        accr[nf] = (f32x4){0.f, 0.f, 0.f, 0.f};
        accs[nf] = (f32x4){0.f, 0.f, 0.f, 0.f};
    }
#pragma unroll
    for (int ks = 0; ks < 4; ++ks) {
        const size_t wi = ((size_t)(ks * 8 + wave) * 64 + lane) * 8;
        bf16x8 rh = *(const bf16x8*)(Wrh_i + wi);
        bf16x8 sh = *(const bf16x8*)(Wsh_i + wi);
#pragma unroll
        for (int nf = 0; nf < 4; ++nf) {
            const int col = nf * 16 + l15;
            const int byo = (ks * 64 + lq * 16) ^ ((col & 7) << 4);
            bf16x8 g = *(const bf16x8*)(lds + 2 * XPLANE + col * 256 + byo);
            accr[nf] = __builtin_amdgcn_mfma_f32_16x16x32_bf16(rh, g, accr[nf], 0, 0, 0);
            accs[nf] = __builtin_amdgcn_mfma_f32_16x16x32_bf16(sh, g, accs[nf], 0, 0, 0);
        }
    }

    const int nt = TFULL - tile0 < 64 ? TFULL - tile0 : 64;
    const float4 brv = *(const float4*)(br + ch0);
    const float4 bsv = *(const float4*)(bs + ch0);
#pragma unroll
    for (int nf = 0; nf < 4; ++nf) {
        const int n = nf * 16 + l15;
        if (n < nt) {
            const int c = tile0 + n;
            const int byo = (ch0 * 2) ^ ((n & 7) << 4);
            bf16x4 ih = *(const bf16x4*)(lds + XPLANE + n * 256 + byo);
            const size_t off = xbase + (size_t)c * RC + ch0;
            bf16x4 il = *(const bf16x4*)(curl + off);
            bf16x4 oh, ol;
            float sk[4];
#pragma unroll
            for (int r = 0; r < 4; ++r) {
                float inv = bf2f((unsigned short)ih[r]) + bf2f((unsigned short)il[r]);
                float rv = accr[nf][r] + ((const float*)&brv)[r] + inv;
                unsigned short h = f2bf(rv);
                oh[r] = (short)h;
                ol[r] = (short)f2bf(rv - bf2f(h));
                sk[r] = accs[nf][r] + ((const float*)&bsv)[r];
            }
            *(bf16x4*)(nxth + off) = oh;
            *(bf16x4*)(nxtl + off) = ol;
            if (c >= TFULL - SKIP_SZ) {
                float* sp = skip + ((size_t)b * RC + ch0) * SKIP_SZ + (c - (TFULL - SKIP_SZ));
#pragma unroll
                for (int r = 0; r < 4; ++r) sp[(size_t)r * SKIP_SZ] = sk[r];
            }
        }
    }
}

// ---------------------------------------------------------------------------
// Stage X-hi into RX region: cols [0,RXC) = global [t0-STGHB, t0+64).
// ---------------------------------------------------------------------------
template<int RXC, int STGHB>
__device__ __forceinline__ void stage_x(char* lds, const unsigned short* __restrict__ curh,
                                        size_t xbase, int t0)
{
    const int tid  = threadIdx.x;
    const int lane = tid & 63;
    const int wave = tid >> 6;
    const int l15  = lane & 15, lq = lane >> 4;
#pragma unroll
    for (int j = wave; j < RXC / 4; j += 8) {
        const int c4  = j * 4;
        const int col = c4 + lq;
        const int chs = l15 ^ (col & 7);
        int g = t0 - STGHB + col;
        g = g < 0 ? 0 : (g > TFULL - 1 ? TFULL - 1 : g);
        const unsigned short* gsrc = curh + xbase + (size_t)g * RC + chs * 8;
        __builtin_amdgcn_global_load_lds(GLB1(gsrc), LDS3(lds + c4 * 256), 16, 0, 0);
    }
}

// ---------------------------------------------------------------------------
// One fused sub-block (1-product GEMMs). Template'd offsets (R11 lesson).
// ---------------------------------------------------------------------------
template<int NF, int Q0v, int Q1v, int HI, bool FIRST, bool LAST>
__device__ __forceinline__ void wn_sub(
    char* lds, const int srcOff, const int dstOff,
    const unsigned short* __restrict__ Wdh_i,
    const unsigned short* __restrict__ Wrh_i,
    const unsigned short* __restrict__ Wsh_i,
    const float* __restrict__ br, const float* __restrict__ bs,
    const unsigned short* __restrict__ curl,
    unsigned short* __restrict__ nxth, unsigned short* __restrict__ nxtl,
    float* __restrict__ skip, int t0, int b, int nt)
{
    constexpr int FH = HI >> 4;
    const int tid  = threadIdx.x;
    const int lane = tid & 63;
    const int wave = tid >> 6;
    const int l15  = lane & 15, lq = lane >> 4;
    const int ch0  = wave * 16 + lq * 4;
    const size_t xbase = (size_t)b * TFULL * RC;

    // ---- dilated conv (1-product)
    f32x4 a[NF];
#pragma unroll
    for (int nf = 0; nf < NF; ++nf) a[nf] = (f32x4){0.f, 0.f, 0.f, 0.f};
#pragma unroll
    for (int ks = 0; ks < 8; ++ks) {
        const int tap = ks >> 2;
        const int kk  = ks & 3;
        const size_t wi = ((size_t)(ks * 8 + wave) * 64 + lane) * 8;
        bf16x8 ah = *(const bf16x8*)(Wdh_i + wi);
#pragma unroll
        for (int nf = 0; nf < NF; ++nf) {
            const int pc  = nf * 16 + l15 + (tap ? Q1v : Q0v);
            const int byo = pc * 256 + ((kk * 64 + lq * 16) ^ ((pc & 7) << 4));
            bf16x8 bh = *(const bf16x8*)(lds + srcOff + byo);
            a[nf] = __builtin_amdgcn_mfma_f32_16x16x32_bf16(ah, bh, a[nf], 0, 0, 0);
        }
    }

    // ---- gate -> dst
#pragma unroll
    for (int nf = 0; nf < NF; ++nf) {
        const int gc  = nf * 16 + l15;
        const int byo = gc * 256 + ((ch0 * 2) ^ ((gc & 7) << 4));
        bf16x4 hv;
#pragma unroll
        for (int r = 0; r < 4; ++r)
            hv[r] = (short)f2bf(gatef(a[nf][r]));
        *(bf16x4*)(lds + dstOff + byo) = hv;
    }
    __syncthreads();

    // ---- res & skip (1-product each)
    f32x4 rr[NF], ss[NF];
#pragma unroll
    for (int nf = 0; nf < NF; ++nf) {
        rr[nf] = (f32x4){0.f, 0.f, 0.f, 0.f};
        ss[nf] = (f32x4){0.f, 0.f, 0.f, 0.f};
    }
#pragma unroll
    for (int ks = 0; ks < 4; ++ks) {
        const size_t wi = ((size_t)(ks * 8 + wave) * 64 + lane) * 8;
        bf16x8 rh = *(const bf16x8*)(Wrh_i + wi);
        bf16x8 sh = *(const bf16x8*)(Wsh_i + wi);
#pragma unroll
        for (int nf = 0; nf < NF; ++nf) {
            const int gc  = nf * 16 + l15;
            const int byo = gc * 256 + ((ks * 64 + lq * 16) ^ ((gc & 7) << 4));
            bf16x8 g = *(const bf16x8*)(lds + dstOff + byo);
            rr[nf] = __builtin_amdgcn_mfma_f32_16x16x32_bf16(rh, g, rr[nf], 0, 0, 0);
            ss[nf] = __builtin_amdgcn_mfma_f32_16x16x32_bf16(sh, g, ss[nf], 0, 0, 0);
        }
    }
    __syncthreads();

    // ---- epilogue
    const float4 brv = *(const float4*)(br + ch0);
    const float4 bsv = *(const float4*)(bs + ch0);
#pragma unroll
    for (int nf = 0; nf < NF; ++nf) {
        const int yc = nf * 16 + l15;
        const int c  = t0 - HI + yc;
        const int pc = yc + Q1v;
        bf16x4 ph = *(const bf16x4*)(lds + srcOff + pc * 256 + ((ch0 * 2) ^ ((pc & 7) << 4)));
        float resid[4];
#pragma unroll
        for (int r = 0; r < 4; ++r) resid[r] = bf2f((unsigned short)ph[r]);
        if constexpr (FIRST) {
            int cg = c < 0 ? 0 : (c > TFULL - 1 ? TFULL - 1 : c);
            bf16x4 xl = *(const bf16x4*)(curl + xbase + (size_t)cg * RC + ch0);
#pragma unroll
            for (int r = 0; r < 4; ++r) resid[r] += bf2f((unsigned short)xl[r]);
        }
        float yv[4], sk[4];
#pragma unroll
        for (int r = 0; r < 4; ++r) {
            yv[r] = rr[nf][r] + ((const float*)&brv)[r] + resid[r];
            sk[r] = ss[nf][r] + ((const float*)&bsv)[r];
        }
        if constexpr (LAST) {
            const int lc = yc;
            if (lc < nt) {
                bf16x4 oh, ol;
#pragma unroll
                for (int r = 0; r < 4; ++r) {
                    unsigned short h = f2bf(yv[r]);
                    oh[r] = (short)h;
                    ol[r] = (short)f2bf(yv[r] - bf2f(h));
                }
                const size_t off = xbase + (size_t)c * RC + ch0;
                *(bf16x4*)(nxth + off) = oh;
                *(bf16x4*)(nxtl + off) = ol;
                if (c >= TFULL - SKIP_SZ) {
                    float* sp = skip + ((size_t)b * RC + ch0) * SKIP_SZ + (c - (TFULL - SKIP_SZ));
#pragma unroll
                    for (int r = 0; r < 4; ++r) sp[(size_t)r * SKIP_SZ] = sk[r];
                }
            }
        } else {
            bf16x4 yh4;
#pragma unroll
            for (int r = 0; r < 4; ++r)
                yh4[r] = (short)f2bf(yv[r]);   // intermediate y lo dropped
            *(bf16x4*)(lds + dstOff + yc * 256 + ((ch0 * 2) ^ ((yc & 7) << 4))) = yh4;
            if (nf >= FH) {
                const int lc = yc - HI;
                if (lc < nt && c >= TFULL - SKIP_SZ) {
                    float* sp = skip + ((size_t)b * RC + ch0) * SKIP_SZ + (c - (TFULL - SKIP_SZ));
#pragma unroll
                    for (int r = 0; r < 4; ++r) sp[(size_t)r * SKIP_SZ] = sk[r];
                }
            }
        }
    }
}

// ---------------------------------------------------------------------------
// Fused QUINT (d = 1,2,4,8,16). H = 64,48,32,16,0; STGHB = 68.
// ---------------------------------------------------------------------------
__global__ __launch_bounds__(512, 4) void wn_quint(
    const unsigned short* __restrict__ curh, const unsigned short* __restrict__ curl,
    unsigned short* __restrict__ nxth, unsigned short* __restrict__ nxtl,
    const unsigned short* __restrict__ Wdh,
    const unsigned short* __restrict__ Wrh,
    const unsigned short* __restrict__ Wsh,
    const float* __restrict__ br_all, const float* __restrict__ bs_all,
    float* __restrict__ out, int blk, int col0)
{
    constexpr int STGHB = 68, RXC = 132;
    constexpr int RB = RXC * 256;            // 33792
    __shared__ char lds[RB + 8 * 16 * 256];  // 66560 B -> 2 WG/CU

    const int u  = blockIdx.x;
    const int b  = u & 3;
    const int t0 = col0 + (u >> 2) * 64;
    const size_t xbase = (size_t)b * TFULL * RC;
    const int nt = TFULL - t0 < 64 ? TFULL - t0 : 64;
    const size_t SKB = (size_t)BATCH * RC * SKIP_SZ;

    stage_x<RXC, STGHB>(lds, curh, xbase, t0);
    __syncthreads();

#define WQ(j) Wdh + (size_t)(blk+j)*32768, \
              Wrh + (size_t)(blk+j)*16384, \
              Wsh + (size_t)(blk+j)*16384, \
              br_all + (size_t)(blk+j)*RC, bs_all + (size_t)(blk+j)*RC, \
              curl, nxth, nxtl, out + (size_t)(blk+j)*SKB, t0, b, nt

    wn_sub<8,  3,  4, 64, true,  false>(lds, 0,  RB, WQ(0));
    __syncthreads();
    wn_sub<7, 14, 16, 48, false, false>(lds, RB, 0,  WQ(1));
    __syncthreads();
    wn_sub<6, 12, 16, 32, false, false>(lds, 0,  RB, WQ(2));
    __syncthreads();
    wn_sub<5,  8, 16, 16, false, false>(lds, RB, 0,  WQ(3));
    __syncthreads();
    wn_sub<4,  0, 16,  0, false, true >(lds, 0,  RB, WQ(4));
#undef WQ
}

// ---------------------------------------------------------------------------
// Fused PAIR (d = 32,64). H = 64,0; STGHB = 96.
// ---------------------------------------------------------------------------
__global__ __launch_bounds__(512, 4) void wn_pair2(
    const unsigned short* __restrict__ curh, const unsigned short* __restrict__ curl,
    unsigned short* __restrict__ nxth, unsigned short* __restrict__ nxtl,
    const unsigned short* __restrict__ Wdh,
    const unsigned short* __restrict__ Wrh,
    const unsigned short* __restrict__ Wsh,
    const float* __restrict__ br_all, const float* __restrict__ bs_all,
    float* __restrict__ out, int blk, int col0)
{
    constexpr int STGHB = 96, RXC = 160;
    constexpr int RB = RXC * 256;            // 40960
    __shared__ char lds[RB + 8 * 16 * 256];  // 73728 B -> 2 WG/CU

    const int u  = blockIdx.x;
    const int b  = u & 3;
    const int t0 = col0 + (u >> 2) * 64;
    const size_t xbase = (size_t)b * TFULL * RC;
    const int nt = TFULL - t0 < 64 ? TFULL - t0 : 64;
    const size_t SKB = (size_t)BATCH * RC * SKIP_SZ;

    stage_x<RXC, STGHB>(lds, curh, xbase, t0);
    __syncthreads();

#define WQ(j) Wdh + (size_t)(blk+j)*32768, \
              Wrh + (size_t)(blk+j)*16384, \
              Wsh + (size_t)(blk+j)*16384, \
              br_all + (size_t)(blk+j)*RC, bs_all + (size_t)(blk+j)*RC, \
              curl, nxth, nxtl, out + (size_t)(blk+j)*SKB, t0, b, nt

    wn_sub<8, 0, 32, 64, true,  false>(lds, 0,  RB, WQ(0));
    __syncthreads();
    wn_sub<4, 0, 64,  0, false, true >(lds, RB, 0,  WQ(1));
#undef WQ
}

extern "C" void kernel_launch(void* const* d_in, const int* in_sizes, int n_in,
                              void* d_out, int out_size, void* d_ws, size_t ws_size,
                              hipStream_t stream) {
    const float* x  = (const float*)d_in[0];
    const float* Wd = (const float*)d_in[1];
    const float* Wr = (const float*)d_in[2];
    const float* br = (const float*)d_in[3];
    const float* Ws = (const float*)d_in[4];
    const float* bs = (const float*)d_in[5];
    float* out = (float*)d_out;

    const size_t SLOT = (size_t)BATCH * TFULL * RC;
    unsigned short* Xs0h = (unsigned short*)d_ws;
    unsigned short* Xs0l = Xs0h + SLOT;
    unsigned short* Xs1h = Xs0l + SLOT;
    unsigned short* Xs1l = Xs1h + SLOT;
    unsigned short* Wdh = Xs1l + SLOT;
    unsigned short* Wrh = Wdh + (size_t)NB * 32768;
    unsigned short* Wsh = Wrh + (size_t)NB * 16384;

    prepass<<<dim3(3328), dim3(256), 0, stream>>>(
        x, Wd, Wr, Ws, Xs0h, Xs0l, Wdh, Wrh, Wsh);

    int L = TFULL;
    int pp = 0;
    for (int s = 0; s < 4; ++s) {
        // quint: blocks s*10 .. s*10+4 (d = 1,2,4,8,16)
        {
            const int i = s * 10;
            const int Lout = L - 31;
            const int col0 = TFULL - Lout;
            const int units = ((Lout + 63) >> 6) * BATCH;
            unsigned short* curh = pp ? Xs1h : Xs0h;
            unsigned short* curl = pp ? Xs1l : Xs0l;
            unsigned short* nxth = pp ? Xs0h : Xs1h;
            unsigned short* nxtl = pp ? Xs0l : Xs1l;
            wn_quint<<<dim3(units), dim3(512), 0, stream>>>(
                curh, curl, nxth, nxtl, Wdh, Wrh, Wsh, br, bs, out, i, col0);
            pp ^= 1;
            L = Lout;
        }
        // pair: blocks s*10+5, +6 (d = 32, 64)
        {
            const int i = s * 10 + 5;
            const int Lout = L - 96;
            const int col0 = TFULL - Lout;
            const int units = ((Lout + 63) >> 6) * BATCH;
            unsigned short* curh = pp ? Xs1h : Xs0h;
            unsigned short* curl = pp ? Xs1l : Xs0l;
            unsigned short* nxth = pp ? Xs0h : Xs1h;
            unsigned short* nxtl = pp ? Xs0l : Xs1l;
            wn_pair2<<<dim3(units), dim3(512), 0, stream>>>(
                curh, curl, nxth, nxtl, Wdh, Wrh, Wsh, br, bs, out, i, col0);
            pp ^= 1;
            L = Lout;
        }
        // singles: d = 128, 256, 512
        for (int q = 7; q < 10; ++q) {
            const int i = s * 10 + q;
            const int d = 1 << q;
            const int Lout = L - d;
            const int col0 = TFULL - Lout;
            const int units = ((Lout + 63) >> 6) * BATCH;
            unsigned short* curh = pp ? Xs1h : Xs0h;
            unsigned short* curl = pp ? Xs1l : Xs0l;
            unsigned short* nxth = pp ? Xs0h : Xs1h;
            unsigned short* nxtl = pp ? Xs0l : Xs1l;
            wn_step<<<dim3(units), dim3(512), 0, stream>>>(
                curh, curl, nxth, nxtl,
                Wdh + (size_t)i * 32768,
                Wrh + (size_t)i * 16384,
                Wsh + (size_t)i * 16384,
                br + (size_t)i * RC, bs + (size_t)i * RC,
                out + (size_t)i * BATCH * RC * SKIP_SZ, d, col0);
            pp ^= 1;
            L = Lout;
        }
    }
}

// Round 17
// 511.220 us; speedup vs baseline: 1.5789x; 1.0251x over previous
//
#include <hip/hip_runtime.h>

typedef __attribute__((ext_vector_type(8))) short bf16x8;
typedef __attribute__((ext_vector_type(4))) short bf16x4;
typedef __attribute__((ext_vector_type(4))) float f32x4;

#define TFULL 8192
#define RC 128
#define NB 40
#define BATCH 4
#define SKIP_SZ 4096

#define LDS3(p) ((__attribute__((address_space(3))) void*)(p))
#define GLB1(p) ((const __attribute__((address_space(1))) void*)(p))

// ---- single-block kernel LDS ----
#define XPLANE 16384
#define LDS_BYTES (3 * XPLANE)   // 48 KB

__device__ __forceinline__ unsigned short f2bf(float f) {
    unsigned u = __builtin_bit_cast(unsigned, f);
    u += 0x7FFFu + ((u >> 16) & 1u);          // round-to-nearest-even
    return (unsigned short)(u >> 16);
}
__device__ __forceinline__ float bf2f(unsigned short h) {
    unsigned u = ((unsigned)h) << 16;
    return __builtin_bit_cast(float, u);
}
// tanh(y)*sigmoid(y) via one fast exp (clamped; saturation exact).
__device__ __forceinline__ float gatef(float y) {
    float yc = fminf(fmaxf(y, -30.f), 30.f);
    float e  = __expf(-yc);
    float e2 = e * e;
    return (1.f - e2) * __builtin_amdgcn_rcpf(1.f + e2)
                      * __builtin_amdgcn_rcpf(1.f + e);
}

// ---------------------------------------------------------------------------
// Merged pre-pass: blocks [0,2048) transpose+split x (hi/lo, exact spine);
// blocks [2048,3328) pack weights hi-only into A-fragment layout.
// ---------------------------------------------------------------------------
__global__ __launch_bounds__(256) void prepass(
    const float* __restrict__ x,
    const float* __restrict__ Wd, const float* __restrict__ Wr, const float* __restrict__ Ws,
    unsigned short* __restrict__ Xh, unsigned short* __restrict__ Xl,
    unsigned short* __restrict__ Wdh,
    unsigned short* __restrict__ Wrh,
    unsigned short* __restrict__ Wsh)
{
    __shared__ float t[32][65];
    const int bx  = blockIdx.x;
    const int tid = threadIdx.x;
    if (bx < 2048) {
        const int col0 = (bx & 127) * 64;
        const int ch0  = ((bx >> 7) & 3) * 32;
        const int b    = bx >> 9;
        const int tx = tid & 63, ty = tid >> 6;
#pragma unroll
        for (int i = 0; i < 8; ++i) {
            int ch = ty + i * 4;
            t[ch][tx] = x[((size_t)(b * RC + ch0 + ch)) * TFULL + col0 + tx];
        }
        __syncthreads();
        for (int idx = tid; idx < 64 * 32; idx += 256) {
            int col = idx >> 5, ch = idx & 31;
            float v = t[ch][col];
            unsigned short h = f2bf(v);
            unsigned short l = f2bf(v - bf2f(h));
            size_t off = ((size_t)(b * TFULL + col0 + col)) * RC + ch0 + ch;
            Xh[off] = h;
            Xl[off] = l;
        }
        return;
    }
    const int Nd = NB * 4096;
    const int Nr = NB * 2048;
    int id = (bx - 2048) * 256 + tid;
    const float* src;
    unsigned short* dh;
    int blk, rloc;
    bool dil = false;
    size_t dbase;
    if (id < Nd)               { dil = true; blk = id >> 12; rloc = id & 4095; dh = Wdh; src = Wd; dbase = (size_t)id * 8; }
    else if (id < Nd + Nr)     { int u = id - Nd;      blk = u >> 11; rloc = u & 2047; dh = Wrh; src = Wr; dbase = (size_t)u * 8; }
    else if (id < Nd + 2 * Nr) { int u = id - Nd - Nr; blk = u >> 11; rloc = u & 2047; dh = Wsh; src = Ws; dbase = (size_t)u * 8; }
    else return;
    const int ks = rloc >> 9, mf = (rloc >> 6) & 7, lane = rloc & 63;
    const int m = mf * 16 + (lane & 15);
    const int kb = ks * 32 + ((lane >> 4) << 3);
    bf16x8 hv;
#pragma unroll
    for (int j = 0; j < 8; ++j) {
        int k = kb + j;
        float w;
        if (dil) {
            int tap = k >> 7, i = k & 127;
            w = src[((((size_t)blk * 128 + m) * 128) + i) * 2 + tap];
        } else {
            w = src[(((size_t)blk * 128 + m) * 128) + k];
        }
        hv[j] = (short)f2bf(w);
    }
    *(bf16x8*)(dh + dbase) = hv;
}

// ---------------------------------------------------------------------------
// Single-block step (unchanged from R16).
// ---------------------------------------------------------------------------
__global__ __launch_bounds__(512, 4) void wn_step(
    const unsigned short* __restrict__ curh, const unsigned short* __restrict__ curl,
    unsigned short* __restrict__ nxth, unsigned short* __restrict__ nxtl,
    const unsigned short* __restrict__ Wdh_i,
    const unsigned short* __restrict__ Wrh_i,
    const unsigned short* __restrict__ Wsh_i,
    const float* __restrict__ br, const float* __restrict__ bs,
    float* __restrict__ skip, int d, int col0)
{
    __shared__ char lds[LDS_BYTES];

    const int tid  = threadIdx.x;
    const int lane = tid & 63;
    const int wave = tid >> 6;
    const int l15  = lane & 15, lq = lane >> 4;
    const int u    = blockIdx.x;
    const int b    = u & 3;
    const int tile0 = col0 + (u >> 2) * 64;
    const size_t xbase = (size_t)b * TFULL * RC;

#pragma unroll
    for (int r = 0; r < 4; ++r) {
        const int j   = wave * 4 + r;
        const int tap = j >> 4;
        const int c4  = (j & 15) * 4;
        const int col = c4 + lq;
        const int chs = l15 ^ (col & 7);
        int cg_ = tile0 + col;
        cg_ = cg_ > TFULL - 1 ? TFULL - 1 : cg_;
        if (!tap) cg_ -= d;
        const unsigned short* gsrc = curh + xbase + (size_t)cg_ * RC + chs * 8;
        char* ldst = lds + tap * XPLANE + c4 * 256;
        __builtin_amdgcn_global_load_lds(GLB1(gsrc), LDS3(ldst), 16, 0, 0);
    }
    __syncthreads();

    f32x4 acc[4];
#pragma unroll
    for (int nf = 0; nf < 4; ++nf) acc[nf] = (f32x4){0.f, 0.f, 0.f, 0.f};

#pragma unroll
    for (int ks = 0; ks < 8; ++ks) {
        const int tap = ks >> 2;
        const int kk  = ks & 3;
        const size_t wi = ((size_t)(ks * 8 + wave) * 64 + lane) * 8;
        bf16x8 ah = *(const bf16x8*)(Wdh_i + wi);
#pragma unroll
        for (int nf = 0; nf < 4; ++nf) {
            const int col = nf * 16 + l15;
            const int byo = (kk * 64 + lq * 16) ^ ((col & 7) << 4);
            bf16x8 bh = *(const bf16x8*)(lds + tap * XPLANE + col * 256 + byo);
            acc[nf] = __builtin_amdgcn_mfma_f32_16x16x32_bf16(ah, bh, acc[nf], 0, 0, 0);
        }
    }

    const int ch0 = wave * 16 + lq * 4;
#pragma unroll
    for (int nf = 0; nf < 4; ++nf) {
        const int n   = nf * 16 + l15;
        const int byo = (ch0 * 2) ^ ((n & 7) << 4);
        bf16x4 hv;
#pragma unroll
        for (int r = 0; r < 4; ++r)
            hv[r] = (short)f2bf(gatef(acc[nf][r]));
        *(bf16x4*)(lds + 2 * XPLANE + n * 256 + byo) = hv;
    }
    __syncthreads();

    f32x4 accr[4], accs[4];
#pragma unroll
    for (int nf = 0; nf < 4; ++nf) {
        accr[nf] = (f32x4){0.f, 0.f, 0.f, 0.f};
        accs[nf] = (f32x4){0.f, 0.f, 0.f, 0.f};
    }
#pragma unroll
    for (int ks = 0; ks < 4; ++ks) {
        const size_t wi = ((size_t)(ks * 8 + wave) * 64 + lane) * 8;
        bf16x8 rh = *(const bf16x8*)(Wrh_i + wi);
        bf16x8 sh = *(const bf16x8*)(Wsh_i + wi);
#pragma unroll
        for (int nf = 0; nf < 4; ++nf) {
            const int col = nf * 16 + l15;
            const int byo = (ks * 64 + lq * 16) ^ ((col & 7) << 4);
            bf16x8 g = *(const bf16x8*)(lds + 2 * XPLANE + col * 256 + byo);
            accr[nf] = __builtin_amdgcn_mfma_f32_16x16x32_bf16(rh, g, accr[nf], 0, 0, 0);
            accs[nf] = __builtin_amdgcn_mfma_f32_16x16x32_bf16(sh, g, accs[nf], 0, 0, 0);
        }
    }

    const int nt = TFULL - tile0 < 64 ? TFULL - tile0 : 64;
    const float4 brv = *(const float4*)(br + ch0);
    const float4 bsv = *(const float4*)(bs + ch0);
#pragma unroll
    for (int nf = 0; nf < 4; ++nf) {
        const int n = nf * 16 + l15;
        if (n < nt) {
            const int c = tile0 + n;
            const int byo = (ch0 * 2) ^ ((n & 7) << 4);
            bf16x4 ih = *(const bf16x4*)(lds + XPLANE + n * 256 + byo);
            const size_t off = xbase + (size_t)c * RC + ch0;
            bf16x4 il = *(const bf16x4*)(curl + off);
            bf16x4 oh, ol;
            float sk[4];
#pragma unroll
            for (int r = 0; r < 4; ++r) {
                float inv = bf2f((unsigned short)ih[r]) + bf2f((unsigned short)il[r]);
                float rv = accr[nf][r] + ((const float*)&brv)[r] + inv;
                unsigned short h = f2bf(rv);
                oh[r] = (short)h;
                ol[r] = (short)f2bf(rv - bf2f(h));
                sk[r] = accs[nf][r] + ((const float*)&bsv)[r];
            }
            *(bf16x4*)(nxth + off) = oh;
            *(bf16x4*)(nxtl + off) = ol;
            if (c >= TFULL - SKIP_SZ) {
                float* sp = skip + ((size_t)b * RC + ch0) * SKIP_SZ + (c - (TFULL - SKIP_SZ));
#pragma unroll
                for (int r = 0; r < 4; ++r) sp[(size_t)r * SKIP_SZ] = sk[r];
            }
        }
    }
}

// ---------------------------------------------------------------------------
// Stage X-hi: cols [0,RXC) = global [t0-STGHB, t0-STGHB+RXC).
// ---------------------------------------------------------------------------
template<int RXC, int STGHB>
__device__ __forceinline__ void stage_x(char* lds, const unsigned short* __restrict__ curh,
                                        size_t xbase, int t0)
{
    const int tid  = threadIdx.x;
    const int lane = tid & 63;
    const int wave = tid >> 6;
    const int l15  = lane & 15, lq = lane >> 4;
#pragma unroll
    for (int j = wave; j < RXC / 4; j += 8) {
        const int c4  = j * 4;
        const int col = c4 + lq;
        const int chs = l15 ^ (col & 7);
        int g = t0 - STGHB + col;
        g = g < 0 ? 0 : (g > TFULL - 1 ? TFULL - 1 : g);
        const unsigned short* gsrc = curh + xbase + (size_t)g * RC + chs * 8;
        __builtin_amdgcn_global_load_lds(GLB1(gsrc), LDS3(lds + c4 * 256), 16, 0, 0);
    }
}

// ---------------------------------------------------------------------------
// Fused sub-block. SEPY: epilogue writes y to a separate region (yOff) so the
// rs->epilogue WAR barrier is eliminated (2 barriers/sub incl. caller's).
// Non-aligned HI supported via per-element skip masking. 1-product GEMMs.
// ---------------------------------------------------------------------------
template<int NF, int Q0v, int Q1v, int HI, bool FIRST, bool LAST, bool SEPY>
__device__ __forceinline__ void wn_sub(
    char* lds, const int srcOff, const int gOff, const int yOff,
    const unsigned short* __restrict__ Wdh_i,
    const unsigned short* __restrict__ Wrh_i,
    const unsigned short* __restrict__ Wsh_i,
    const float* __restrict__ br, const float* __restrict__ bs,
    const unsigned short* __restrict__ curl,
    unsigned short* __restrict__ nxth, unsigned short* __restrict__ nxtl,
    float* __restrict__ skip, int t0, int b, int nt)
{
    const int tid  = threadIdx.x;
    const int lane = tid & 63;
    const int wave = tid >> 6;
    const int l15  = lane & 15, lq = lane >> 4;
    const int ch0  = wave * 16 + lq * 4;
    const size_t xbase = (size_t)b * TFULL * RC;

    // ---- dilated conv (1-product)
    f32x4 a[NF];
#pragma unroll
    for (int nf = 0; nf < NF; ++nf) a[nf] = (f32x4){0.f, 0.f, 0.f, 0.f};
#pragma unroll
    for (int ks = 0; ks < 8; ++ks) {
        const int tap = ks >> 2;
        const int kk  = ks & 3;
        const size_t wi = ((size_t)(ks * 8 + wave) * 64 + lane) * 8;
        bf16x8 ah = *(const bf16x8*)(Wdh_i + wi);
#pragma unroll
        for (int nf = 0; nf < NF; ++nf) {
            const int pc  = nf * 16 + l15 + (tap ? Q1v : Q0v);
            const int byo = pc * 256 + ((kk * 64 + lq * 16) ^ ((pc & 7) << 4));
            bf16x8 bh = *(const bf16x8*)(lds + srcOff + byo);
            a[nf] = __builtin_amdgcn_mfma_f32_16x16x32_bf16(ah, bh, a[nf], 0, 0, 0);
        }
    }

    // ---- gate -> gOff
#pragma unroll
    for (int nf = 0; nf < NF; ++nf) {
        const int gc  = nf * 16 + l15;
        const int byo = gc * 256 + ((ch0 * 2) ^ ((gc & 7) << 4));
        bf16x4 hv;
#pragma unroll
        for (int r = 0; r < 4; ++r)
            hv[r] = (short)f2bf(gatef(a[nf][r]));
        *(bf16x4*)(lds + gOff + byo) = hv;
    }
    __syncthreads();

    // ---- res & skip (1-product each)
    f32x4 rr[NF], ss[NF];
#pragma unroll
    for (int nf = 0; nf < NF; ++nf) {
        rr[nf] = (f32x4){0.f, 0.f, 0.f, 0.f};
        ss[nf] = (f32x4){0.f, 0.f, 0.f, 0.f};
    }
#pragma unroll
    for (int ks = 0; ks < 4; ++ks) {
        const size_t wi = ((size_t)(ks * 8 + wave) * 64 + lane) * 8;
        bf16x8 rh = *(const bf16x8*)(Wrh_i + wi);
        bf16x8 sh = *(const bf16x8*)(Wsh_i + wi);
#pragma unroll
        for (int nf = 0; nf < NF; ++nf) {
            const int gc  = nf * 16 + l15;
            const int byo = gc * 256 + ((ks * 64 + lq * 16) ^ ((gc & 7) << 4));
            bf16x8 g = *(const bf16x8*)(lds + gOff + byo);
            rr[nf] = __builtin_amdgcn_mfma_f32_16x16x32_bf16(rh, g, rr[nf], 0, 0, 0);
            ss[nf] = __builtin_amdgcn_mfma_f32_16x16x32_bf16(sh, g, ss[nf], 0, 0, 0);
        }
    }
    if constexpr (!SEPY) __syncthreads();   // WAR: y overwrites gOff

    // ---- epilogue
    const float4 brv = *(const float4*)(br + ch0);
    const float4 bsv = *(const float4*)(bs + ch0);
#pragma unroll
    for (int nf = 0; nf < NF; ++nf) {
        const int yc = nf * 16 + l15;
        const int c  = t0 - HI + yc;
        const int pc = yc + Q1v;
        bf16x4 ph = *(const bf16x4*)(lds + srcOff + pc * 256 + ((ch0 * 2) ^ ((pc & 7) << 4)));
        float resid[4];
#pragma unroll
        for (int r = 0; r < 4; ++r) resid[r] = bf2f((unsigned short)ph[r]);
        if constexpr (FIRST) {
            int cg = c < 0 ? 0 : (c > TFULL - 1 ? TFULL - 1 : c);
            bf16x4 xl = *(const bf16x4*)(curl + xbase + (size_t)cg * RC + ch0);
#pragma unroll
            for (int r = 0; r < 4; ++r) resid[r] += bf2f((unsigned short)xl[r]);
        }
        float yv[4], sk[4];
#pragma unroll
        for (int r = 0; r < 4; ++r) {
            yv[r] = rr[nf][r] + ((const float*)&brv)[r] + resid[r];
            sk[r] = ss[nf][r] + ((const float*)&bsv)[r];
        }
        if constexpr (LAST) {
            if (yc < nt) {
                bf16x4 oh, ol;
#pragma unroll
                for (int r = 0; r < 4; ++r) {
                    unsigned short h = f2bf(yv[r]);
                    oh[r] = (short)h;
                    ol[r] = (short)f2bf(yv[r] - bf2f(h));
                }
                const size_t off = xbase + (size_t)c * RC + ch0;
                *(bf16x4*)(nxth + off) = oh;
                *(bf16x4*)(nxtl + off) = ol;
                if (c >= TFULL - SKIP_SZ) {
                    float* sp = skip + ((size_t)b * RC + ch0) * SKIP_SZ + (c - (TFULL - SKIP_SZ));
#pragma unroll
                    for (int r = 0; r < 4; ++r) sp[(size_t)r * SKIP_SZ] = sk[r];
                }
            }
        } else {
            bf16x4 yh4;
#pragma unroll
            for (int r = 0; r < 4; ++r)
                yh4[r] = (short)f2bf(yv[r]);   // intermediate y lo dropped
            *(bf16x4*)(lds + yOff + yc * 256 + ((ch0 * 2) ^ ((yc & 7) << 4))) = yh4;
            const int lc = yc - HI;
            if (lc >= 0 && lc < nt && c >= TFULL - SKIP_SZ) {
                float* sp = skip + ((size_t)b * RC + ch0) * SKIP_SZ + (c - (TFULL - SKIP_SZ));
#pragma unroll
                for (int r = 0; r < 4; ++r) sp[(size_t)r * SKIP_SZ] = sk[r];
            }
        }
    }
}

// ---------------------------------------------------------------------------
// Fused QUINT (d = 1,2,4,8,16), exact halos H = 30,28,24,16,0; STGHB = 31.
// Three 104-col regions rotate (src / gated / y) -> 2 barriers per sub.
// ---------------------------------------------------------------------------
__global__ __launch_bounds__(512, 4) void wn_quint(
    const unsigned short* __restrict__ curh, const unsigned short* __restrict__ curl,
    unsigned short* __restrict__ nxth, unsigned short* __restrict__ nxtl,
    const unsigned short* __restrict__ Wdh,
    const unsigned short* __restrict__ Wrh,
    const unsigned short* __restrict__ Wsh,
    const float* __restrict__ br_all, const float* __restrict__ bs_all,
    float* __restrict__ out, int blk, int col0)
{
    constexpr int RA = 0, RB = 26624, RCg = 53248;   // 3 x 104 cols x 256 B
    __shared__ char lds[79872];                      // 78 KB -> 2 WG/CU

    const int u  = blockIdx.x;
    const int b  = u & 3;
    const int t0 = col0 + (u >> 2) * 64;
    const size_t xbase = (size_t)b * TFULL * RC;
    const int nt = TFULL - t0 < 64 ? TFULL - t0 : 64;
    const size_t SKB = (size_t)BATCH * RC * SKIP_SZ;

    stage_x<96, 31>(lds, curh, xbase, t0);   // cols [t0-31, t0+65)
    __syncthreads();

#define WQ(j) Wdh + (size_t)(blk+j)*32768, \
              Wrh + (size_t)(blk+j)*16384, \
              Wsh + (size_t)(blk+j)*16384, \
              br_all + (size_t)(blk+j)*RC, bs_all + (size_t)(blk+j)*RC, \
              curl, nxth, nxtl, out + (size_t)(blk+j)*SKB, t0, b, nt

    wn_sub<6, 0,  1, 30, true,  false, true>(lds, RA,  RB,  RCg, WQ(0));
    __syncthreads();
    wn_sub<6, 0,  2, 28, false, false, true>(lds, RCg, RA,  RB,  WQ(1));
    __syncthreads();
    wn_sub<6, 0,  4, 24, false, false, true>(lds, RB,  RCg, RA,  WQ(2));
    __syncthreads();
    wn_sub<5, 0,  8, 16, false, false, true>(lds, RA,  RB,  RCg, WQ(3));
    __syncthreads();
    wn_sub<4, 0, 16,  0, false, true,  true>(lds, RCg, RA,  RA,  WQ(4));
#undef WQ
}

// ---------------------------------------------------------------------------
// Fused PAIR (d = 32,64). H = 64,0; STGHB = 96. Overwrite mode (3 barriers).
// ---------------------------------------------------------------------------
__global__ __launch_bounds__(512, 4) void wn_pair2(
    const unsigned short* __restrict__ curh, const unsigned short* __restrict__ curl,
    unsigned short* __restrict__ nxth, unsigned short* __restrict__ nxtl,
    const unsigned short* __restrict__ Wdh,
    const unsigned short* __restrict__ Wrh,
    const unsigned short* __restrict__ Wsh,
    const float* __restrict__ br_all, const float* __restrict__ bs_all,
    float* __restrict__ out, int blk, int col0)
{
    constexpr int RB = 40960;                // after 160-col X region
    __shared__ char lds[RB + 8 * 16 * 256];  // 73728 B -> 2 WG/CU

    const int u  = blockIdx.x;
    const int b  = u & 3;
    const int t0 = col0 + (u >> 2) * 64;
    const size_t xbase = (size_t)b * TFULL * RC;
    const int nt = TFULL - t0 < 64 ? TFULL - t0 : 64;
    const size_t SKB = (size_t)BATCH * RC * SKIP_SZ;

    stage_x<160, 96>(lds, curh, xbase, t0);
    __syncthreads();

#define WQ(j) Wdh + (size_t)(blk+j)*32768, \
              Wrh + (size_t)(blk+j)*16384, \
              Wsh + (size_t)(blk+j)*16384, \
              br_all + (size_t)(blk+j)*RC, bs_all + (size_t)(blk+j)*RC, \
              curl, nxth, nxtl, out + (size_t)(blk+j)*SKB, t0, b, nt

    wn_sub<8, 0, 32, 64, true,  false, false>(lds, 0,  RB, RB, WQ(0));
    __syncthreads();
    wn_sub<4, 0, 64,  0, false, true,  false>(lds, RB, 0,  0,  WQ(1));
#undef WQ
}

extern "C" void kernel_launch(void* const* d_in, const int* in_sizes, int n_in,
                              void* d_out, int out_size, void* d_ws, size_t ws_size,
                              hipStream_t stream) {
    const float* x  = (const float*)d_in[0];
    const float* Wd = (const float*)d_in[1];
    const float* Wr = (const float*)d_in[2];
    const float* br = (const float*)d_in[3];
    const float* Ws = (const float*)d_in[4];
    const float* bs = (const float*)d_in[5];
    float* out = (float*)d_out;

    const size_t SLOT = (size_t)BATCH * TFULL * RC;
    unsigned short* Xs0h = (unsigned short*)d_ws;
    unsigned short* Xs0l = Xs0h + SLOT;
    unsigned short* Xs1h = Xs0l + SLOT;
    unsigned short* Xs1l = Xs1h + SLOT;
    unsigned short* Wdh = Xs1l + SLOT;
    unsigned short* Wrh = Wdh + (size_t)NB * 32768;
    unsigned short* Wsh = Wrh + (size_t)NB * 16384;

    prepass<<<dim3(3328), dim3(256), 0, stream>>>(
        x, Wd, Wr, Ws, Xs0h, Xs0l, Wdh, Wrh, Wsh);

    int L = TFULL;
    int pp = 0;
    for (int s = 0; s < 4; ++s) {
        // quint: blocks s*10 .. s*10+4 (d = 1,2,4,8,16)
        {
            const int i = s * 10;
            const int Lout = L - 31;
            const int col0 = TFULL - Lout;
            const int units = ((Lout + 63) >> 6) * BATCH;
            unsigned short* curh = pp ? Xs1h : Xs0h;
            unsigned short* curl = pp ? Xs1l : Xs0l;
            unsigned short* nxth = pp ? Xs0h : Xs1h;
            unsigned short* nxtl = pp ? Xs0l : Xs1l;
            wn_quint<<<dim3(units), dim3(512), 0, stream>>>(
                curh, curl, nxth, nxtl, Wdh, Wrh, Wsh, br, bs, out, i, col0);
            pp ^= 1;
            L = Lout;
        }
        // pair: blocks s*10+5, +6 (d = 32, 64)
        {
            const int i = s * 10 + 5;
            const int Lout = L - 96;
            const int col0 = TFULL - Lout;
            const int units = ((Lout + 63) >> 6) * BATCH;
            unsigned short* curh = pp ? Xs1h : Xs0h;
            unsigned short* curl = pp ? Xs1l : Xs0l;
            unsigned short* nxth = pp ? Xs0h : Xs1h;
            unsigned short* nxtl = pp ? Xs0l : Xs1l;
            wn_pair2<<<dim3(units), dim3(512), 0, stream>>>(
                curh, curl, nxth, nxtl, Wdh, Wrh, Wsh, br, bs, out, i, col0);
            pp ^= 1;
            L = Lout;
        }
        // singles: d = 128, 256, 512
        for (int q = 7; q < 10; ++q) {
            const int i = s * 10 + q;
            const int d = 1 << q;
            const int Lout = L - d;
            const int col0 = TFULL - Lout;
            const int units = ((Lout + 63) >> 6) * BATCH;
            unsigned short* curh = pp ? Xs1h : Xs0h;
            unsigned short* curl = pp ? Xs1l : Xs0l;
            unsigned short* nxth = pp ? Xs0h : Xs1h;
            unsigned short* nxtl = pp ? Xs0l : Xs1l;
            wn_step<<<dim3(units), dim3(512), 0, stream>>>(
                curh, curl, nxth, nxtl,
                Wdh + (size_t)i * 32768,
                Wrh + (size_t)i * 16384,
                Wsh + (size_t)i * 16384,
                br + (size_t)i * RC, bs + (size_t)i * RC,
                out + (size_t)i * BATCH * RC * SKIP_SZ, d, col0);
            pp ^= 1;
            L = Lout;
        }
    }
}